// Round 4
// baseline (821.723 us; speedup 1.0000x reference)
//
#include <hip/hip_runtime.h>
#include <hip/hip_fp16.h>
#include <hip/hip_cooperative_groups.h>

namespace cg = cooperative_groups;

// GraphSAGE 3-layer, SINGLE cooperative mega-kernel (R4).
// Phases (grid.sync between): P0 zero+hist(LDS)+fp32->fp16 cvt | P1 btot |
// P2 scan+reserve+scatter | P3 per-bucket CSR build | P4 agg+GEMM1 |
// P5 agg+GEMM2+W3 dots | P6 final gather.
// Rationale: R3 showed ~60-70us of inter-dispatch gaps across 7 launches;
// persistent blocks also keep the per-block bucket histogram in LDS.
// LDS union 26112B -> 6 blocks/CU; grid = maxActiveBlocks*256CU (<=1536).
//
// ws: offs | scol | xh h[(N+1)*64] | h1 h[(N+1)*64] | scr | tarr f[N] | sarr f[N]
//     scr = ebuf[E] | btot[256] | cursor[256]

#define CH 64
#define BKT_SHIFT 9
#define BKT_ROWS 512
#define ALDS_STRIDE 72   // halves; 144B rows: 16B-aligned, <=2-way banks
#define WLDS_STRIDE 132  // halves; 264B rows: 8B-aligned, <=2-way banks

typedef _Float16 half4_t __attribute__((ext_vector_type(4)));
typedef float f32x4 __attribute__((ext_vector_type(4)));

struct SMemCSR { int lhist[256]; int ts[256]; int base[256]; int h[256]; };
struct SMemBld { int cnt[512]; int loff[512]; int ts[256]; int gg[2]; };
struct SMemMM  { unsigned short alds[64 * ALDS_STRIDE];    // 9216 B
                 unsigned short wlds[64 * WLDS_STRIDE]; }; // 16896 B
union SMem { SMemCSR csr; SMemBld bld; SMemMM mm; };       // 26112 B

// ---- mean-aggregate a node pair into LDS rows rA, rA+1 (fp16) ----
__device__ __forceinline__ void agg_pair(const float4* __restrict__ X4,
                                         const int* __restrict__ offs,
                                         const int* __restrict__ scol,
                                         __half* __restrict__ alds,
                                         int nA, int rA, int lane,
                                         int N, int Em1) {
    int nB = nA + 1;
    int sA = 0, eA = 0, sB = 0, eB = 0;
    if (nA < N) { sA = offs[nA]; eA = offs[nA + 1]; }
    if (nB < N) { sB = offs[nB]; eB = offs[nB + 1]; }
    int sub = lane & 7;
    int grp = lane >> 3;
    int jA = sA + grp, jB = sB + grp;
    int a0 = scol[min(jA, Em1)];       a0 = (jA < eA)      ? a0 : N;
    int a1 = scol[min(jA + 8, Em1)];   a1 = (jA + 8 < eA)  ? a1 : N;
    int a2 = scol[min(jA + 16, Em1)];  a2 = (jA + 16 < eA) ? a2 : N;
    int a3 = scol[min(jA + 24, Em1)];  a3 = (jA + 24 < eA) ? a3 : N;
    int b0 = scol[min(jB, Em1)];       b0 = (jB < eB)      ? b0 : N;
    int b1 = scol[min(jB + 8, Em1)];   b1 = (jB + 8 < eB)  ? b1 : N;
    int b2 = scol[min(jB + 16, Em1)];  b2 = (jB + 16 < eB) ? b2 : N;
    int b3 = scol[min(jB + 24, Em1)];  b3 = (jB + 24 < eB) ? b3 : N;
    float4 rA0 = X4[(size_t)a0 * 8 + sub];
    float4 rA1 = X4[(size_t)a1 * 8 + sub];
    float4 rA2 = X4[(size_t)a2 * 8 + sub];
    float4 rA3 = X4[(size_t)a3 * 8 + sub];
    float4 rB0 = X4[(size_t)b0 * 8 + sub];
    float4 rB1 = X4[(size_t)b1 * 8 + sub];
    float4 rB2 = X4[(size_t)b2 * 8 + sub];
    float4 rB3 = X4[(size_t)b3 * 8 + sub];
    float a[8], b[8];
    {
        const __half2* h0 = (const __half2*)&rA0;
        const __half2* h1 = (const __half2*)&rA1;
        const __half2* h2 = (const __half2*)&rA2;
        const __half2* h3 = (const __half2*)&rA3;
#pragma unroll
        for (int p = 0; p < 4; ++p) {
            __half2 sm = __hadd2(__hadd2(h0[p], h1[p]), __hadd2(h2[p], h3[p]));
            float2 f = __half22float2(sm);
            a[2 * p] = f.x;
            a[2 * p + 1] = f.y;
        }
        const __half2* g0 = (const __half2*)&rB0;
        const __half2* g1 = (const __half2*)&rB1;
        const __half2* g2 = (const __half2*)&rB2;
        const __half2* g3 = (const __half2*)&rB3;
#pragma unroll
        for (int p = 0; p < 4; ++p) {
            __half2 sm = __hadd2(__hadd2(g0[p], g1[p]), __hadd2(g2[p], g3[p]));
            float2 f = __half22float2(sm);
            b[2 * p] = f.x;
            b[2 * p + 1] = f.y;
        }
    }
    for (int j = jA + 32; j < eA; j += 8) {  // rare tail: deg > 32
        float4 r = X4[(size_t)scol[j] * 8 + sub];
        const __half2* h = (const __half2*)&r;
#pragma unroll
        for (int p = 0; p < 4; ++p) {
            float2 f = __half22float2(h[p]);
            a[2 * p]     += f.x;
            a[2 * p + 1] += f.y;
        }
    }
    for (int j = jB + 32; j < eB; j += 8) {
        float4 r = X4[(size_t)scol[j] * 8 + sub];
        const __half2* h = (const __half2*)&r;
#pragma unroll
        for (int p = 0; p < 4; ++p) {
            float2 f = __half22float2(h[p]);
            b[2 * p]     += f.x;
            b[2 * p + 1] += f.y;
        }
    }
#pragma unroll
    for (int off = 32; off >= 8; off >>= 1)
#pragma unroll
        for (int k = 0; k < 8; ++k) {
            a[k] += __shfl_down(a[k], off, 64);
            b[k] += __shfl_down(b[k], off, 64);
        }
    if (lane < 8) {
        float invA = (eA > sA) ? 1.0f / (float)(eA - sA) : 1.0f;
        float invB = (eB > sB) ? 1.0f / (float)(eB - sB) : 1.0f;
        union { __half2 h[4]; float4 f; } u;
        u.h[0] = __floats2half2_rn(a[0] * invA, a[1] * invA);
        u.h[1] = __floats2half2_rn(a[2] * invA, a[3] * invA);
        u.h[2] = __floats2half2_rn(a[4] * invA, a[5] * invA);
        u.h[3] = __floats2half2_rn(a[6] * invA, a[7] * invA);
        *(float4*)(alds + rA * ALDS_STRIDE + sub * 8) = u.f;
        union { __half2 h[4]; float4 f; } w;
        w.h[0] = __floats2half2_rn(b[0] * invB, b[1] * invB);
        w.h[1] = __floats2half2_rn(b[2] * invB, b[3] * invB);
        w.h[2] = __floats2half2_rn(b[4] * invB, b[5] * invB);
        w.h[3] = __floats2half2_rn(b[6] * invB, b[7] * invB);
        *(float4*)(alds + (rA + 1) * ALDS_STRIDE + sub * 8) = w.f;
    }
}

// ---- convert W (64x128 fp32) into LDS fp16, stride-padded ----
__device__ __forceinline__ void w_to_lds(const float* __restrict__ W,
                                         __half* __restrict__ wlds, int t) {
    for (int i = t; i < 64 * 32; i += 256) {
        int o = i >> 5;
        int kq = (i & 31) * 4;
        float4 v = *(const float4*)(W + o * 128 + kq);
        half4_t h = {(_Float16)v.x, (_Float16)v.y, (_Float16)v.z, (_Float16)v.w};
        *(half4_t*)(wlds + o * WLDS_STRIDE + kq) = h;
    }
}

// MFMA 16x16x16_f16 layout:
//   A: lane l holds A[l&15][4*(l>>4)+r]
//   B: lane l holds B[4*(l>>4)+r][l&15]   (= W[l&15][4*(l>>4)+r] here)
//   D: lane l holds D[4*(l>>4)+r][l&15]

__global__ __launch_bounds__(256, 6) void k_mega(
    const float* __restrict__ X,
    const int* __restrict__ row, const int* __restrict__ col,
    const float* __restrict__ W1, const float* __restrict__ b1,
    const float* __restrict__ W2, const float* __restrict__ b2,
    const float* __restrict__ W3, const float* __restrict__ b3,
    float* __restrict__ out,
    int* __restrict__ offs, int* __restrict__ scol,
    __half* __restrict__ xh, __half* __restrict__ h1,
    int* __restrict__ ebuf, int* __restrict__ btot, int* __restrict__ cursor,
    int N, int E, int nbk) {
    cg::grid_group grid = cg::this_grid();
    __shared__ SMem sm;
    int t = threadIdx.x;
    int blk = blockIdx.x;
    int G = gridDim.x;
    int per_blk = (E + G - 1) / G;
    int es = blk * per_blk;
    int ee = min(es + per_blk, E);
    int Em1 = E - 1;

    // ---- P0: zero globals (block 0), local bucket hist (LDS), fp32->fp16 ----
    sm.csr.lhist[t] = 0;
    if (blk == 0) { btot[t] = 0; cursor[t] = 0; }
    __syncthreads();
    for (int i = es + t; i < ee; i += 256)
        atomicAdd(&sm.csr.lhist[row[i] >> BKT_SHIFT], 1);
    int Mf = N * CH;
    for (int idx = (blk * 256 + t) * 4; idx < Mf; idx += G * 256 * 4) {
        float4 v = *(const float4*)(X + idx);
        union { __half2 h2[2]; float2 f; } u;
        u.h2[0] = __floats2half2_rn(v.x, v.y);
        u.h2[1] = __floats2half2_rn(v.z, v.w);
        *(float2*)(xh + idx) = u.f;
    }
    if (blk == 0 && t < 16) {  // zero dummy row N of xh and h1
        float4 z = {0.f, 0.f, 0.f, 0.f};
        if (t < 8)
            ((float4*)(xh + (size_t)N * CH))[t] = z;
        else
            ((float4*)(h1 + (size_t)N * CH))[t - 8] = z;
    }
    __syncthreads();
    int myh = sm.csr.lhist[t];  // this block's count for bucket t
    grid.sync();

    // ---- P1: accumulate bucket totals ----
    if (myh) atomicAdd(&btot[t], myh);
    grid.sync();

    // ---- P2: scan btot, reserve range per (block,bucket), scatter ----
    {
        int v = btot[t];
        sm.csr.ts[t] = v;
        __syncthreads();
        for (int off = 1; off < 256; off <<= 1) {
            int u = (t >= off) ? sm.csr.ts[t - off] : 0;
            __syncthreads();
            sm.csr.ts[t] += u;
            __syncthreads();
        }
        int bstart = sm.csr.ts[t] - v;  // exclusive scan
        sm.csr.base[t] = bstart + (myh ? atomicAdd(&cursor[t], myh) : 0);
        sm.csr.h[t] = 0;
        __syncthreads();
        for (int i = es + t; i < ee; i += 256) {
            int r = row[i];
            int b = r >> BKT_SHIFT;
            int p = sm.csr.base[b] + atomicAdd(&sm.csr.h[b], 1);
            ebuf[p] = ((r & (BKT_ROWS - 1)) << 17) | col[i];
        }
    }
    grid.sync();

    // ---- P3: per-bucket CSR build (blocks < nbk) ----
    if (blk < nbk) {
        int v = btot[t];
        sm.bld.ts[t] = v;
        __syncthreads();
        for (int off = 1; off < 256; off <<= 1) {
            int u = (t >= off) ? sm.bld.ts[t - off] : 0;
            __syncthreads();
            sm.bld.ts[t] += u;
            __syncthreads();
        }
        if (t == blk) { sm.bld.gg[0] = sm.bld.ts[t] - v; sm.bld.gg[1] = sm.bld.ts[t]; }
        sm.bld.cnt[t] = 0;
        sm.bld.cnt[t + 256] = 0;
        __syncthreads();
        int g0 = sm.bld.gg[0], g1 = sm.bld.gg[1];
        for (int i = g0 + t; i < g1; i += 256)
            atomicAdd(&sm.bld.cnt[((unsigned)ebuf[i]) >> 17], 1);
        __syncthreads();
        int c0 = sm.bld.cnt[2 * t], c1 = sm.bld.cnt[2 * t + 1];
        sm.bld.ts[t] = c0 + c1;
        __syncthreads();
        for (int off = 1; off < 256; off <<= 1) {
            int u = (t >= off) ? sm.bld.ts[t - off] : 0;
            __syncthreads();
            sm.bld.ts[t] += u;
            __syncthreads();
        }
        int ex = sm.bld.ts[t] - (c0 + c1);
        sm.bld.loff[2 * t] = ex;
        sm.bld.loff[2 * t + 1] = ex + c0;
        __syncthreads();
        int r0 = blk << BKT_SHIFT;
        for (int r = t; r < BKT_ROWS; r += 256)
            if (r0 + r < N) offs[r0 + r] = g0 + sm.bld.loff[r];
        sm.bld.cnt[t] = 0;
        sm.bld.cnt[t + 256] = 0;
        __syncthreads();
        for (int i = g0 + t; i < g1; i += 256) {
            unsigned v2 = (unsigned)ebuf[i];
            int rl = v2 >> 17;
            int p = atomicAdd(&sm.bld.cnt[rl], 1);
            scol[g0 + sm.bld.loff[rl] + p] = (int)(v2 & 0x1FFFFu);
        }
    }
    if (blk == 0 && t == 0) offs[N] = E;
    grid.sync();

    int ntiles = (N + 63) / 64;
    int wv = t >> 6;
    int lane = t & 63;
    int lrow = lane & 15;
    int lk = lane >> 4;
    __half* alds = (__half*)sm.mm.alds;
    __half* wlds = (__half*)sm.mm.wlds;

    // ---- P4: layer 1 — agg->LDS, h1 = relu(cat(xh,agg).W1^T + b1) ----
    {
        const float4* X4 = (const float4*)xh;
        w_to_lds(W1, wlds, t);
        for (int tile = blk; tile < ntiles; tile += G) {
            __syncthreads();
            int nb = tile * 64;
#pragma unroll 1
            for (int i = 0; i < 8; ++i) {
                int rA = wv * 16 + 2 * i;
                agg_pair(X4, offs, scol, alds, nb + rA, rA, lane, N, Em1);
            }
            __syncthreads();
            int nt = nb + wv * 16;
            const __half* xrow = xh + (size_t)min(nt + lrow, N) * CH + 4 * lk;
            half4_t af[8];
#pragma unroll
            for (int kc = 0; kc < 4; ++kc) {
                af[kc]     = *(const half4_t*)(xrow + kc * 16);
                af[kc + 4] = *(const half4_t*)(alds + (wv * 16 + lrow) * ALDS_STRIDE + kc * 16 + 4 * lk);
            }
            f32x4 acc[4];
#pragma unroll
            for (int ct = 0; ct < 4; ++ct) acc[ct] = (f32x4){0.f, 0.f, 0.f, 0.f};
#pragma unroll
            for (int kc = 0; kc < 8; ++kc)
#pragma unroll
                for (int ct = 0; ct < 4; ++ct) {
                    half4_t bf = *(const half4_t*)(wlds + (ct * 16 + lrow) * WLDS_STRIDE + kc * 16 + 4 * lk);
                    acc[ct] = __builtin_amdgcn_mfma_f32_16x16x16f16(af[kc], bf, acc[ct], 0, 0, 0);
                }
#pragma unroll
            for (int ct = 0; ct < 4; ++ct) {
                float bv = b1[ct * 16 + lrow];
#pragma unroll
                for (int r = 0; r < 4; ++r) {
                    int gn = nt + 4 * lk + r;
                    if (gn < N) {
                        float v = fmaxf(acc[ct][r] + bv, 0.f);
                        h1[(size_t)gn * CH + ct * 16 + lrow] = __float2half(v);
                    }
                }
            }
        }
    }
    grid.sync();

    // ---- P5: layer 2 + layer-3 dots -> tarr/sarr ----
    {
        float* tarr = out;  // placeholder silenced below; real pointers passed in
        (void)tarr;
    }
    {
        const float4* X4 = (const float4*)h1;
        w_to_lds(W2, wlds, t);
        // tarr/sarr live right after the scr region; recover from ebuf base:
        float* tarr = (float*)(((__half*)ebuf) + (size_t)N * CH);
        float* sarr = tarr + N;
        for (int tile = blk; tile < ntiles; tile += G) {
            __syncthreads();
            int nb = tile * 64;
#pragma unroll 1
            for (int i = 0; i < 8; ++i) {
                int rA = wv * 16 + 2 * i;
                agg_pair(X4, offs, scol, alds, nb + rA, rA, lane, N, Em1);
            }
            __syncthreads();
            int nt = nb + wv * 16;
            const __half* xrow = h1 + (size_t)min(nt + lrow, N) * CH + 4 * lk;
            half4_t af[8];
#pragma unroll
            for (int kc = 0; kc < 4; ++kc) {
                af[kc]     = *(const half4_t*)(xrow + kc * 16);
                af[kc + 4] = *(const half4_t*)(alds + (wv * 16 + lrow) * ALDS_STRIDE + kc * 16 + 4 * lk);
            }
            f32x4 acc[4];
#pragma unroll
            for (int ct = 0; ct < 4; ++ct) acc[ct] = (f32x4){0.f, 0.f, 0.f, 0.f};
#pragma unroll
            for (int kc = 0; kc < 8; ++kc)
#pragma unroll
                for (int ct = 0; ct < 4; ++ct) {
                    half4_t bf = *(const half4_t*)(wlds + (ct * 16 + lrow) * WLDS_STRIDE + kc * 16 + 4 * lk);
                    acc[ct] = __builtin_amdgcn_mfma_f32_16x16x16f16(af[kc], bf, acc[ct], 0, 0, 0);
                }
            float bv[4], w3s[4], w3a[4];
#pragma unroll
            for (int ct = 0; ct < 4; ++ct) {
                bv[ct]  = b2[ct * 16 + lrow];
                w3s[ct] = W3[ct * 16 + lrow];
                w3a[ct] = W3[64 + ct * 16 + lrow];
            }
#pragma unroll
            for (int r = 0; r < 4; ++r) {
                float tp = 0.f, sp = 0.f;
#pragma unroll
                for (int ct = 0; ct < 4; ++ct) {
                    float v = fmaxf(acc[ct][r] + bv[ct], 0.f);
                    tp += v * w3s[ct];
                    sp += v * w3a[ct];
                }
#pragma unroll
                for (int off = 1; off <= 8; off <<= 1) {
                    tp += __shfl_xor(tp, off, 16);
                    sp += __shfl_xor(sp, off, 16);
                }
                int gn = nt + 4 * lk + r;
                if (lrow == 0 && gn < N) {
                    tarr[gn] = tp;
                    sarr[gn] = sp;
                }
            }
        }
    }
    grid.sync();

    // ---- P6: out[n] = t[n] + mean_j s[col_j] + b3 ----
    {
        float* tarr = (float*)(((__half*)ebuf) + (size_t)N * CH);
        float* sarr = tarr + N;
        float b3v = b3[0];
        for (int n = blk * 256 + t; n < N; n += G * 256) {
            int s = offs[n], e = offs[n + 1];
            float s0 = 0.f, s1 = 0.f, s2 = 0.f, s3 = 0.f;
            int j = s;
            for (; j + 4 <= e; j += 4) {
                s0 += sarr[scol[j]];
                s1 += sarr[scol[j + 1]];
                s2 += sarr[scol[j + 2]];
                s3 += sarr[scol[j + 3]];
            }
            for (; j < e; ++j) s0 += sarr[scol[j]];
            float inv = (e > s) ? 1.0f / (float)(e - s) : 1.0f;
            out[n] = tarr[n] + ((s0 + s1) + (s2 + s3)) * inv + b3v;
        }
    }
}

extern "C" void kernel_launch(void* const* d_in, const int* in_sizes, int n_in,
                              void* d_out, int out_size, void* d_ws, size_t ws_size,
                              hipStream_t stream) {
    const float* x   = (const float*)d_in[0];
    const int* eidx  = (const int*)d_in[1];
    const float* W1  = (const float*)d_in[2];
    const float* b1  = (const float*)d_in[3];
    const float* W2  = (const float*)d_in[4];
    const float* b2  = (const float*)d_in[5];
    const float* W3  = (const float*)d_in[6];
    const float* b3  = (const float*)d_in[7];
    float* out = (float*)d_out;

    const int N = in_sizes[0] / CH;
    const int E = in_sizes[1] / 2;
    const int* row = eidx;
    const int* col = eidx + E;

    int offs_sz = ((N + 1 + 3) / 4) * 4;
    int e_sz    = ((E + 3) / 4) * 4;
    size_t tbl  = (size_t)(N + 1) * CH;  // halves per table (incl. zero row)

    int* offs    = (int*)d_ws;                        // offs_sz ints
    int* scol    = offs + offs_sz;                    // e_sz ints
    __half* xh   = (__half*)(scol + e_sz);            // tbl halves
    __half* h1   = xh + tbl;                          // tbl halves
    __half* scr  = h1 + tbl;                          // scratch region (N*CH halves)
    // tarr/sarr live after scr; the kernel recovers them from ebuf base.
    int* ebuf   = (int*)scr;                          // E ints (dead after P3)
    int nbk     = (N + BKT_ROWS - 1) >> BKT_SHIFT;
    int* btot   = ebuf + e_sz;                        // 256 ints
    int* cursor = btot + 256;                         // 256 ints

    int maxB = 0;
    hipOccupancyMaxActiveBlocksPerMultiprocessor(&maxB, k_mega, 256, 0);
    if (maxB < 1) maxB = 1;
    if (maxB > 6) maxB = 6;          // LDS 26112B -> 6 blocks/CU expected
    int G = maxB * 256;              // 256 CUs on gfx950

    const float* Xp = x; const int* rowp = row; const int* colp = col;
    const float* W1p = W1; const float* b1p = b1;
    const float* W2p = W2; const float* b2p = b2;
    const float* W3p = W3; const float* b3p = b3;
    float* outp = out;
    int* offsp = offs; int* scolp = scol;
    __half* xhp = xh; __half* h1p = h1;
    int* ebufp = ebuf; int* btotp = btot; int* cursorp = cursor;
    int Nv = N, Ev = E, nbkv = nbk;
    void* args[] = {&Xp, &rowp, &colp, &W1p, &b1p, &W2p, &b2p, &W3p, &b3p,
                    &outp, &offsp, &scolp, &xhp, &h1p, &ebufp, &btotp,
                    &cursorp, &Nv, &Ev, &nbkv};
    hipLaunchCooperativeKernel(k_mega, dim3(G), dim3(256), args, 0, stream);
}

// Round 5
// 754.984 us; speedup vs baseline: 1.0884x; 1.0884x over previous
//
#include <hip/hip_runtime.h>
#include <hip/hip_fp16.h>

// GraphSAGE 3-layer, SINGLE persistent kernel with hand-rolled grid barrier
// (R5). R4's cg::grid.sync cost ~100us/sync; this uses one atomicAdd +
// agent-scope spin per block (monotonic counter, no reset races; counter
// zeroed by the preceding memset each replay). Regular launch, grid =
// 6 blocks/CU x 256 CU co-resident (LDS 26112B -> exactly 6/CU).
// Phases: P0 hist(LDS)+cvt+btot | B | P2 scan+reserve+scatter | B |
// P3 per-bucket CSR build | B | P4 agg+GEMM1 | B | P5 agg+GEMM2+dots | B |
// P6 final gather.  5 barriers, 2 graph nodes total.
//
// ws: offs | scol | xh h[(N+1)*64] | h1 h[(N+1)*64] | scr | tarr f[N] | sarr f[N]
//     scr = ebuf[E] | btot[256] | cursor[256] | bar[1]

#define CH 64
#define BKT_SHIFT 9
#define BKT_ROWS 512
#define ALDS_STRIDE 72   // halves; 144B rows: 16B-aligned, <=2-way banks
#define WLDS_STRIDE 132  // halves; 264B rows: 8B-aligned, <=2-way banks

typedef _Float16 half4_t __attribute__((ext_vector_type(4)));
typedef float f32x4 __attribute__((ext_vector_type(4)));

struct SMemCSR { int lhist[256]; int ts[256]; int base[256]; int h[256]; };
struct SMemBld { int cnt[512]; int loff[512]; int ts[256]; int gg[2]; };
struct SMemMM  { unsigned short alds[64 * ALDS_STRIDE];    // 9216 B
                 unsigned short wlds[64 * WLDS_STRIDE]; }; // 16896 B
union SMem { SMemCSR csr; SMemBld bld; SMemMM mm; };       // 26112 B

// ---- grid barrier: monotonic counter, one arrival per block ----
__device__ __forceinline__ void gbar(unsigned* cnt, unsigned target) {
    __syncthreads();
    if (threadIdx.x == 0) {
        __threadfence();  // release prior writes to agent scope
        __hip_atomic_fetch_add(cnt, 1u, __ATOMIC_RELAXED,
                               __HIP_MEMORY_SCOPE_AGENT);
        while (__hip_atomic_load(cnt, __ATOMIC_RELAXED,
                                 __HIP_MEMORY_SCOPE_AGENT) < target)
            __builtin_amdgcn_s_sleep(2);
        __threadfence();  // acquire
    }
    __syncthreads();
}

// ---- mean-aggregate a node pair into LDS rows rA, rA+1 (fp16) ----
__device__ __forceinline__ void agg_pair(const float4* __restrict__ X4,
                                         const int* __restrict__ offs,
                                         const int* __restrict__ scol,
                                         __half* __restrict__ alds,
                                         int nA, int rA, int lane,
                                         int N, int Em1) {
    int nB = nA + 1;
    int sA = 0, eA = 0, sB = 0, eB = 0;
    if (nA < N) { sA = offs[nA]; eA = offs[nA + 1]; }
    if (nB < N) { sB = offs[nB]; eB = offs[nB + 1]; }
    int sub = lane & 7;
    int grp = lane >> 3;
    int jA = sA + grp, jB = sB + grp;
    int a0 = scol[min(jA, Em1)];       a0 = (jA < eA)      ? a0 : N;
    int a1 = scol[min(jA + 8, Em1)];   a1 = (jA + 8 < eA)  ? a1 : N;
    int a2 = scol[min(jA + 16, Em1)];  a2 = (jA + 16 < eA) ? a2 : N;
    int a3 = scol[min(jA + 24, Em1)];  a3 = (jA + 24 < eA) ? a3 : N;
    int b0 = scol[min(jB, Em1)];       b0 = (jB < eB)      ? b0 : N;
    int b1 = scol[min(jB + 8, Em1)];   b1 = (jB + 8 < eB)  ? b1 : N;
    int b2 = scol[min(jB + 16, Em1)];  b2 = (jB + 16 < eB) ? b2 : N;
    int b3 = scol[min(jB + 24, Em1)];  b3 = (jB + 24 < eB) ? b3 : N;
    float4 rA0 = X4[(size_t)a0 * 8 + sub];
    float4 rA1 = X4[(size_t)a1 * 8 + sub];
    float4 rA2 = X4[(size_t)a2 * 8 + sub];
    float4 rA3 = X4[(size_t)a3 * 8 + sub];
    float4 rB0 = X4[(size_t)b0 * 8 + sub];
    float4 rB1 = X4[(size_t)b1 * 8 + sub];
    float4 rB2 = X4[(size_t)b2 * 8 + sub];
    float4 rB3 = X4[(size_t)b3 * 8 + sub];
    float a[8], b[8];
    {
        const __half2* h0 = (const __half2*)&rA0;
        const __half2* h1 = (const __half2*)&rA1;
        const __half2* h2 = (const __half2*)&rA2;
        const __half2* h3 = (const __half2*)&rA3;
#pragma unroll
        for (int p = 0; p < 4; ++p) {
            __half2 sm = __hadd2(__hadd2(h0[p], h1[p]), __hadd2(h2[p], h3[p]));
            float2 f = __half22float2(sm);
            a[2 * p] = f.x;
            a[2 * p + 1] = f.y;
        }
        const __half2* g0 = (const __half2*)&rB0;
        const __half2* g1 = (const __half2*)&rB1;
        const __half2* g2 = (const __half2*)&rB2;
        const __half2* g3 = (const __half2*)&rB3;
#pragma unroll
        for (int p = 0; p < 4; ++p) {
            __half2 sm = __hadd2(__hadd2(g0[p], g1[p]), __hadd2(g2[p], g3[p]));
            float2 f = __half22float2(sm);
            b[2 * p] = f.x;
            b[2 * p + 1] = f.y;
        }
    }
    for (int j = jA + 32; j < eA; j += 8) {  // rare tail: deg > 32
        float4 r = X4[(size_t)scol[j] * 8 + sub];
        const __half2* h = (const __half2*)&r;
#pragma unroll
        for (int p = 0; p < 4; ++p) {
            float2 f = __half22float2(h[p]);
            a[2 * p]     += f.x;
            a[2 * p + 1] += f.y;
        }
    }
    for (int j = jB + 32; j < eB; j += 8) {
        float4 r = X4[(size_t)scol[j] * 8 + sub];
        const __half2* h = (const __half2*)&r;
#pragma unroll
        for (int p = 0; p < 4; ++p) {
            float2 f = __half22float2(h[p]);
            b[2 * p]     += f.x;
            b[2 * p + 1] += f.y;
        }
    }
#pragma unroll
    for (int off = 32; off >= 8; off >>= 1)
#pragma unroll
        for (int k = 0; k < 8; ++k) {
            a[k] += __shfl_down(a[k], off, 64);
            b[k] += __shfl_down(b[k], off, 64);
        }
    if (lane < 8) {
        float invA = (eA > sA) ? 1.0f / (float)(eA - sA) : 1.0f;
        float invB = (eB > sB) ? 1.0f / (float)(eB - sB) : 1.0f;
        union { __half2 h[4]; float4 f; } u;
        u.h[0] = __floats2half2_rn(a[0] * invA, a[1] * invA);
        u.h[1] = __floats2half2_rn(a[2] * invA, a[3] * invA);
        u.h[2] = __floats2half2_rn(a[4] * invA, a[5] * invA);
        u.h[3] = __floats2half2_rn(a[6] * invA, a[7] * invA);
        *(float4*)(alds + rA * ALDS_STRIDE + sub * 8) = u.f;
        union { __half2 h[4]; float4 f; } w;
        w.h[0] = __floats2half2_rn(b[0] * invB, b[1] * invB);
        w.h[1] = __floats2half2_rn(b[2] * invB, b[3] * invB);
        w.h[2] = __floats2half2_rn(b[4] * invB, b[5] * invB);
        w.h[3] = __floats2half2_rn(b[6] * invB, b[7] * invB);
        *(float4*)(alds + (rA + 1) * ALDS_STRIDE + sub * 8) = w.f;
    }
}

// ---- convert W (64x128 fp32) into LDS fp16, stride-padded ----
__device__ __forceinline__ void w_to_lds(const float* __restrict__ W,
                                         __half* __restrict__ wlds, int t) {
    for (int i = t; i < 64 * 32; i += 256) {
        int o = i >> 5;
        int kq = (i & 31) * 4;
        float4 v = *(const float4*)(W + o * 128 + kq);
        half4_t h = {(_Float16)v.x, (_Float16)v.y, (_Float16)v.z, (_Float16)v.w};
        *(half4_t*)(wlds + o * WLDS_STRIDE + kq) = h;
    }
}

// MFMA 16x16x16_f16 layout:
//   A: lane l holds A[l&15][4*(l>>4)+r]
//   B: lane l holds B[4*(l>>4)+r][l&15]   (= W[l&15][4*(l>>4)+r] here)
//   D: lane l holds D[4*(l>>4)+r][l&15]

__global__ __launch_bounds__(256, 6) void k_mega(
    const float* __restrict__ X,
    const int* __restrict__ row, const int* __restrict__ col,
    const float* __restrict__ W1, const float* __restrict__ b1,
    const float* __restrict__ W2, const float* __restrict__ b2,
    const float* __restrict__ W3, const float* __restrict__ b3,
    float* __restrict__ out,
    int* __restrict__ offs, int* __restrict__ scol,
    __half* __restrict__ xh, __half* __restrict__ h1,
    int* __restrict__ ebuf, int* __restrict__ btot, int* __restrict__ cursor,
    unsigned* __restrict__ bar, float* __restrict__ tarr,
    float* __restrict__ sarr, int N, int E, int nbk) {
    __shared__ SMem sm;
    int t = threadIdx.x;
    int blk = blockIdx.x;
    unsigned G = gridDim.x;
    int per_blk = (E + (int)G - 1) / (int)G;
    int es = blk * per_blk;
    int ee = min(es + per_blk, E);
    int Em1 = E - 1;

    // ---- P0: LDS bucket hist, fp32->fp16 cvt, btot accumulate ----
    sm.csr.lhist[t] = 0;
    __syncthreads();
    for (int i = es + t; i < ee; i += 256)
        atomicAdd(&sm.csr.lhist[row[i] >> BKT_SHIFT], 1);
    int Mf = N * CH;
    for (int idx = (blk * 256 + t) * 4; idx < Mf; idx += (int)G * 256 * 4) {
        float4 v = *(const float4*)(X + idx);
        union { __half2 h2[2]; float2 f; } u;
        u.h2[0] = __floats2half2_rn(v.x, v.y);
        u.h2[1] = __floats2half2_rn(v.z, v.w);
        *(float2*)(xh + idx) = u.f;
    }
    if (blk == 0 && t < 16) {  // zero dummy row N of xh and h1
        float4 z = {0.f, 0.f, 0.f, 0.f};
        if (t < 8)
            ((float4*)(xh + (size_t)N * CH))[t] = z;
        else
            ((float4*)(h1 + (size_t)N * CH))[t - 8] = z;
    }
    __syncthreads();
    int myh = sm.csr.lhist[t];  // this block's count for bucket t
    if (myh) atomicAdd(&btot[t], myh);  // btot pre-zeroed by host memset
    gbar(bar, 1 * G);

    // ---- P2: scan btot, reserve range per (block,bucket), scatter ----
    {
        int v = btot[t];
        sm.csr.ts[t] = v;
        __syncthreads();
        for (int off = 1; off < 256; off <<= 1) {
            int u = (t >= off) ? sm.csr.ts[t - off] : 0;
            __syncthreads();
            sm.csr.ts[t] += u;
            __syncthreads();
        }
        int bstart = sm.csr.ts[t] - v;  // exclusive scan
        sm.csr.base[t] = bstart + (myh ? atomicAdd(&cursor[t], myh) : 0);
        sm.csr.h[t] = 0;
        __syncthreads();
        for (int i = es + t; i < ee; i += 256) {
            int r = row[i];
            int b = r >> BKT_SHIFT;
            int p = sm.csr.base[b] + atomicAdd(&sm.csr.h[b], 1);
            ebuf[p] = ((r & (BKT_ROWS - 1)) << 17) | col[i];
        }
    }
    gbar(bar, 2 * G);

    // ---- P3: per-bucket CSR build (blocks < nbk) ----
    if (blk < nbk) {
        int v = btot[t];
        sm.bld.ts[t] = v;
        __syncthreads();
        for (int off = 1; off < 256; off <<= 1) {
            int u = (t >= off) ? sm.bld.ts[t - off] : 0;
            __syncthreads();
            sm.bld.ts[t] += u;
            __syncthreads();
        }
        if (t == blk) { sm.bld.gg[0] = sm.bld.ts[t] - v; sm.bld.gg[1] = sm.bld.ts[t]; }
        sm.bld.cnt[t] = 0;
        sm.bld.cnt[t + 256] = 0;
        __syncthreads();
        int g0 = sm.bld.gg[0], g1 = sm.bld.gg[1];
        for (int i = g0 + t; i < g1; i += 256)
            atomicAdd(&sm.bld.cnt[((unsigned)ebuf[i]) >> 17], 1);
        __syncthreads();
        int c0 = sm.bld.cnt[2 * t], c1 = sm.bld.cnt[2 * t + 1];
        sm.bld.ts[t] = c0 + c1;
        __syncthreads();
        for (int off = 1; off < 256; off <<= 1) {
            int u = (t >= off) ? sm.bld.ts[t - off] : 0;
            __syncthreads();
            sm.bld.ts[t] += u;
            __syncthreads();
        }
        int ex = sm.bld.ts[t] - (c0 + c1);
        sm.bld.loff[2 * t] = ex;
        sm.bld.loff[2 * t + 1] = ex + c0;
        __syncthreads();
        int r0 = blk << BKT_SHIFT;
        for (int r = t; r < BKT_ROWS; r += 256)
            if (r0 + r < N) offs[r0 + r] = g0 + sm.bld.loff[r];
        sm.bld.cnt[t] = 0;
        sm.bld.cnt[t + 256] = 0;
        __syncthreads();
        for (int i = g0 + t; i < g1; i += 256) {
            unsigned v2 = (unsigned)ebuf[i];
            int rl = v2 >> 17;
            int p = atomicAdd(&sm.bld.cnt[rl], 1);
            scol[g0 + sm.bld.loff[rl] + p] = (int)(v2 & 0x1FFFFu);
        }
    }
    if (blk == 0 && t == 0) offs[N] = E;
    gbar(bar, 3 * G);

    int ntiles = (N + 63) / 64;
    int wv = t >> 6;
    int lane = t & 63;
    int lrow = lane & 15;
    int lk = lane >> 4;
    __half* alds = (__half*)sm.mm.alds;
    __half* wlds = (__half*)sm.mm.wlds;

    // ---- P4: layer 1 — agg->LDS, h1 = relu(cat(xh,agg).W1^T + b1) ----
    {
        const float4* X4 = (const float4*)xh;
        w_to_lds(W1, wlds, t);
        for (int tile = blk; tile < ntiles; tile += (int)G) {
            __syncthreads();
            int nb = tile * 64;
#pragma unroll 1
            for (int i = 0; i < 8; ++i) {
                int rA = wv * 16 + 2 * i;
                agg_pair(X4, offs, scol, alds, nb + rA, rA, lane, N, Em1);
            }
            __syncthreads();
            int nt = nb + wv * 16;
            const __half* xrow = xh + (size_t)min(nt + lrow, N) * CH + 4 * lk;
            half4_t af[8];
#pragma unroll
            for (int kc = 0; kc < 4; ++kc) {
                af[kc]     = *(const half4_t*)(xrow + kc * 16);
                af[kc + 4] = *(const half4_t*)(alds + (wv * 16 + lrow) * ALDS_STRIDE + kc * 16 + 4 * lk);
            }
            f32x4 acc[4];
#pragma unroll
            for (int ct = 0; ct < 4; ++ct) acc[ct] = (f32x4){0.f, 0.f, 0.f, 0.f};
#pragma unroll
            for (int kc = 0; kc < 8; ++kc)
#pragma unroll
                for (int ct = 0; ct < 4; ++ct) {
                    half4_t bf = *(const half4_t*)(wlds + (ct * 16 + lrow) * WLDS_STRIDE + kc * 16 + 4 * lk);
                    acc[ct] = __builtin_amdgcn_mfma_f32_16x16x16f16(af[kc], bf, acc[ct], 0, 0, 0);
                }
#pragma unroll
            for (int ct = 0; ct < 4; ++ct) {
                float bv = b1[ct * 16 + lrow];
#pragma unroll
                for (int r = 0; r < 4; ++r) {
                    int gn = nt + 4 * lk + r;
                    if (gn < N) {
                        float v = fmaxf(acc[ct][r] + bv, 0.f);
                        h1[(size_t)gn * CH + ct * 16 + lrow] = __float2half(v);
                    }
                }
            }
        }
    }
    gbar(bar, 4 * G);

    // ---- P5: layer 2 + layer-3 dots -> tarr/sarr ----
    {
        const float4* X4 = (const float4*)h1;
        w_to_lds(W2, wlds, t);
        for (int tile = blk; tile < ntiles; tile += (int)G) {
            __syncthreads();
            int nb = tile * 64;
#pragma unroll 1
            for (int i = 0; i < 8; ++i) {
                int rA = wv * 16 + 2 * i;
                agg_pair(X4, offs, scol, alds, nb + rA, rA, lane, N, Em1);
            }
            __syncthreads();
            int nt = nb + wv * 16;
            const __half* xrow = h1 + (size_t)min(nt + lrow, N) * CH + 4 * lk;
            half4_t af[8];
#pragma unroll
            for (int kc = 0; kc < 4; ++kc) {
                af[kc]     = *(const half4_t*)(xrow + kc * 16);
                af[kc + 4] = *(const half4_t*)(alds + (wv * 16 + lrow) * ALDS_STRIDE + kc * 16 + 4 * lk);
            }
            f32x4 acc[4];
#pragma unroll
            for (int ct = 0; ct < 4; ++ct) acc[ct] = (f32x4){0.f, 0.f, 0.f, 0.f};
#pragma unroll
            for (int kc = 0; kc < 8; ++kc)
#pragma unroll
                for (int ct = 0; ct < 4; ++ct) {
                    half4_t bf = *(const half4_t*)(wlds + (ct * 16 + lrow) * WLDS_STRIDE + kc * 16 + 4 * lk);
                    acc[ct] = __builtin_amdgcn_mfma_f32_16x16x16f16(af[kc], bf, acc[ct], 0, 0, 0);
                }
            float bv[4], w3s[4], w3a[4];
#pragma unroll
            for (int ct = 0; ct < 4; ++ct) {
                bv[ct]  = b2[ct * 16 + lrow];
                w3s[ct] = W3[ct * 16 + lrow];
                w3a[ct] = W3[64 + ct * 16 + lrow];
            }
#pragma unroll
            for (int r = 0; r < 4; ++r) {
                float tp = 0.f, sp = 0.f;
#pragma unroll
                for (int ct = 0; ct < 4; ++ct) {
                    float v = fmaxf(acc[ct][r] + bv[ct], 0.f);
                    tp += v * w3s[ct];
                    sp += v * w3a[ct];
                }
#pragma unroll
                for (int off = 1; off <= 8; off <<= 1) {
                    tp += __shfl_xor(tp, off, 16);
                    sp += __shfl_xor(sp, off, 16);
                }
                int gn = nt + 4 * lk + r;
                if (lrow == 0 && gn < N) {
                    tarr[gn] = tp;
                    sarr[gn] = sp;
                }
            }
        }
    }
    gbar(bar, 5 * G);

    // ---- P6: out[n] = t[n] + mean_j s[col_j] + b3 ----
    {
        float b3v = b3[0];
        for (int n = blk * 256 + t; n < N; n += (int)G * 256) {
            int s = offs[n], e = offs[n + 1];
            float s0 = 0.f, s1 = 0.f, s2 = 0.f, s3 = 0.f;
            int j = s;
            for (; j + 4 <= e; j += 4) {
                s0 += sarr[scol[j]];
                s1 += sarr[scol[j + 1]];
                s2 += sarr[scol[j + 2]];
                s3 += sarr[scol[j + 3]];
            }
            for (; j < e; ++j) s0 += sarr[scol[j]];
            float inv = (e > s) ? 1.0f / (float)(e - s) : 1.0f;
            out[n] = tarr[n] + ((s0 + s1) + (s2 + s3)) * inv + b3v;
        }
    }
}

extern "C" void kernel_launch(void* const* d_in, const int* in_sizes, int n_in,
                              void* d_out, int out_size, void* d_ws, size_t ws_size,
                              hipStream_t stream) {
    const float* x   = (const float*)d_in[0];
    const int* eidx  = (const int*)d_in[1];
    const float* W1  = (const float*)d_in[2];
    const float* b1  = (const float*)d_in[3];
    const float* W2  = (const float*)d_in[4];
    const float* b2  = (const float*)d_in[5];
    const float* W3  = (const float*)d_in[6];
    const float* b3  = (const float*)d_in[7];
    float* out = (float*)d_out;

    const int N = in_sizes[0] / CH;
    const int E = in_sizes[1] / 2;
    const int* row = eidx;
    const int* col = eidx + E;

    int offs_sz = ((N + 1 + 3) / 4) * 4;
    int e_sz    = ((E + 3) / 4) * 4;
    size_t tbl  = (size_t)(N + 1) * CH;  // halves per table (incl. zero row)

    int* offs    = (int*)d_ws;                        // offs_sz ints
    int* scol    = offs + offs_sz;                    // e_sz ints
    __half* xh   = (__half*)(scol + e_sz);            // tbl halves
    __half* h1   = xh + tbl;                          // tbl halves
    __half* scr  = h1 + tbl;                          // scratch region (N*CH halves)
    float* tarr  = (float*)(scr + (size_t)N * CH);    // N floats
    float* sarr  = tarr + N;                          // N floats
    int* ebuf   = (int*)scr;                          // E ints (dead after P3)
    int nbk     = (N + BKT_ROWS - 1) >> BKT_SHIFT;
    int* btot   = ebuf + e_sz;                        // 256 ints
    int* cursor = btot + 256;                         // 256 ints
    unsigned* bar = (unsigned*)(cursor + 256);        // 1 int (barrier counter)

    int maxB = 0;
    hipOccupancyMaxActiveBlocksPerMultiprocessor(&maxB, k_mega, 256, 0);
    if (maxB < 1) maxB = 1;
    if (maxB > 6) maxB = 6;          // LDS 26112B -> 6 blocks/CU
    static int ncu = 0;
    if (!ncu) {
        hipDeviceProp_t p;
        hipGetDeviceProperties(&p, 0);
        ncu = p.multiProcessorCount;
    }
    int G = maxB * ncu;

    // zero btot/cursor/bar (2052 B) each replay
    hipMemsetAsync(btot, 0, 513 * sizeof(int), stream);
    k_mega<<<G, 256, 0, stream>>>(x, row, col, W1, b1, W2, b2, W3, b3, out,
                                  offs, scol, xh, h1, ebuf, btot, cursor,
                                  bar, tarr, sarr, N, E, nbk);
}

// Round 6
// 432.562 us; speedup vs baseline: 1.8997x; 1.7454x over previous
//
#include <hip/hip_runtime.h>
#include <hip/hip_fp16.h>

// GraphSAGE 3-layer (R6). CSR via DIRECT per-node atomic counting (no bucket
// sort, no ebuf middle hop): deg atomics -> block-local scan (loc) + block
// partials (part) -> 1-block partial scan -> place with post-increment trick
// (atomicAdd on loc turns it into the inclusive scan). Node n's edge range:
//   base = part[n>>8]; e = base + loc[n]; s = (n&255) ? base + loc[n-1] : base
// fp16 feature tables (N+1 rows; row N zeroed). Split agg/gemm kernels
// (fusion measured +10us/layer in R3). GEMMs on v_mfma_f32_16x16x16_f16.
// Mega-kernel abandoned: grid barriers cost ~150-200us each at G=1536 (R4/R5).
//
// ws: scol[E] | xh h[(N+1)*64] | h1 h[(N+1)*64] | aggh h[N*64] | tarr f[N] |
//     sarr f[N] | loc[N] | part[512]

#define CH 64
#define NBLK 256    // cntcvt blocks
#define NPLACE 512  // place blocks

typedef _Float16 half4_t __attribute__((ext_vector_type(4)));
typedef float f32x4 __attribute__((ext_vector_type(4)));

// ---- node range helper (composite offs addressing) ----
__device__ __forceinline__ void node_range(const int* __restrict__ loc,
                                           const int* __restrict__ part,
                                           int n, int& s, int& e) {
    int base = part[n >> 8];
    e = base + loc[n];
    s = (n & 255) ? base + loc[n - 1] : base;
}

// ---- deg count (global atomics) + fp32->fp16 cvt + dummy-row zero ----
__global__ __launch_bounds__(256) void k_cntcvt(const int* __restrict__ row,
                                                int* __restrict__ loc,
                                                const float* __restrict__ X,
                                                __half* __restrict__ XH,
                                                __half* __restrict__ H1,
                                                int E, int per_blk,
                                                int Mf, int N) {
    int t = threadIdx.x;
    int s = blockIdx.x * per_blk;
    int e = min(s + per_blk, E);
    for (int i = s + t; i < e; i += 256)
        atomicAdd(&loc[row[i]], 1);
    for (int idx = (blockIdx.x * 256 + t) * 4; idx < Mf; idx += NBLK * 256 * 4) {
        float4 v = *(const float4*)(X + idx);
        union { __half2 h2[2]; float2 f; } u;
        u.h2[0] = __floats2half2_rn(v.x, v.y);
        u.h2[1] = __floats2half2_rn(v.z, v.w);
        *(float2*)(XH + idx) = u.f;
    }
    if (blockIdx.x == 0 && t < 16) {
        float4 z = {0.f, 0.f, 0.f, 0.f};
        if (t < 8)
            ((float4*)(XH + (size_t)N * CH))[t] = z;
        else
            ((float4*)(H1 + (size_t)N * CH))[t - 8] = z;
    }
}

// ---- per-256-node-block exclusive scan (in place) + block totals ----
__global__ __launch_bounds__(256) void k_scanA(int* __restrict__ loc,
                                               int* __restrict__ part, int N) {
    __shared__ int ts[256];
    int t = threadIdx.x;
    int n = blockIdx.x * 256 + t;
    int v = (n < N) ? loc[n] : 0;
    ts[t] = v;
    __syncthreads();
    for (int off = 1; off < 256; off <<= 1) {
        int u = (t >= off) ? ts[t - off] : 0;
        __syncthreads();
        ts[t] += u;
        __syncthreads();
    }
    if (n < N) loc[n] = ts[t] - v;  // exclusive
    if (t == 255) part[blockIdx.x] = ts[255];
}

// ---- 1-block exclusive scan of <=512 partials ----
__global__ __launch_bounds__(256) void k_scanB(int* __restrict__ part, int nb) {
    __shared__ int ts[256];
    int t = threadIdx.x;
    int v0 = (2 * t < nb) ? part[2 * t] : 0;
    int v1 = (2 * t + 1 < nb) ? part[2 * t + 1] : 0;
    ts[t] = v0 + v1;
    __syncthreads();
    for (int off = 1; off < 256; off <<= 1) {
        int u = (t >= off) ? ts[t - off] : 0;
        __syncthreads();
        ts[t] += u;
        __syncthreads();
    }
    int ex = ts[t] - (v0 + v1);
    if (2 * t < nb) part[2 * t] = ex;
    if (2 * t + 1 < nb) part[2 * t + 1] = ex + v0;
}

// ---- place: scol[part[r>>8] + atomicAdd(loc[r],1)] = col ----
__global__ __launch_bounds__(256) void k_place(const int* __restrict__ row,
                                               const int* __restrict__ col,
                                               int* __restrict__ loc,
                                               const int* __restrict__ part,
                                               int* __restrict__ scol,
                                               int E, int per_blk) {
    int t = threadIdx.x;
    int s = blockIdx.x * per_blk;
    int e = min(s + per_blk, E);
    for (int i = s + t; i < e; i += 256) {
        int r = row[i];
        int p = part[r >> 8] + atomicAdd(&loc[r], 1);
        scol[p] = col[i];
    }
}

// ---- Mean-aggregate: one wave per 2 nodes, 8 lanes/edge, 8 gathers in
//      flight, clamp-to-zero-row prefetch, pk_f16 pairwise tree sum ----
__global__ __launch_bounds__(256) void k_agg(const float4* __restrict__ X4,
                                             const int* __restrict__ loc,
                                             const int* __restrict__ part,
                                             const int* __restrict__ scol,
                                             __half* __restrict__ AGGH, int N, int Em1) {
    int wv = threadIdx.x >> 6;
    int lane = threadIdx.x & 63;
    int nA = blockIdx.x * 8 + wv * 2;
    if (nA >= N) return;
    int nB = nA + 1;
    int sA, eA;
    node_range(loc, part, nA, sA, eA);
    int sB = 0, eB = 0;
    if (nB < N) node_range(loc, part, nB, sB, eB);
    int sub = lane & 7;
    int grp = lane >> 3;
    int jA = sA + grp, jB = sB + grp;
    int a0 = scol[min(jA, Em1)];       a0 = (jA < eA)      ? a0 : N;
    int a1 = scol[min(jA + 8, Em1)];   a1 = (jA + 8 < eA)  ? a1 : N;
    int a2 = scol[min(jA + 16, Em1)];  a2 = (jA + 16 < eA) ? a2 : N;
    int a3 = scol[min(jA + 24, Em1)];  a3 = (jA + 24 < eA) ? a3 : N;
    int b0 = scol[min(jB, Em1)];       b0 = (jB < eB)      ? b0 : N;
    int b1 = scol[min(jB + 8, Em1)];   b1 = (jB + 8 < eB)  ? b1 : N;
    int b2 = scol[min(jB + 16, Em1)];  b2 = (jB + 16 < eB) ? b2 : N;
    int b3 = scol[min(jB + 24, Em1)];  b3 = (jB + 24 < eB) ? b3 : N;
    float4 rA0 = X4[(size_t)a0 * 8 + sub];
    float4 rA1 = X4[(size_t)a1 * 8 + sub];
    float4 rA2 = X4[(size_t)a2 * 8 + sub];
    float4 rA3 = X4[(size_t)a3 * 8 + sub];
    float4 rB0 = X4[(size_t)b0 * 8 + sub];
    float4 rB1 = X4[(size_t)b1 * 8 + sub];
    float4 rB2 = X4[(size_t)b2 * 8 + sub];
    float4 rB3 = X4[(size_t)b3 * 8 + sub];
    float a[8], b[8];
    {
        const __half2* h0 = (const __half2*)&rA0;
        const __half2* h1 = (const __half2*)&rA1;
        const __half2* h2 = (const __half2*)&rA2;
        const __half2* h3 = (const __half2*)&rA3;
#pragma unroll
        for (int p = 0; p < 4; ++p) {
            __half2 sm = __hadd2(__hadd2(h0[p], h1[p]), __hadd2(h2[p], h3[p]));
            float2 f = __half22float2(sm);
            a[2 * p] = f.x;
            a[2 * p + 1] = f.y;
        }
        const __half2* g0 = (const __half2*)&rB0;
        const __half2* g1 = (const __half2*)&rB1;
        const __half2* g2 = (const __half2*)&rB2;
        const __half2* g3 = (const __half2*)&rB3;
#pragma unroll
        for (int p = 0; p < 4; ++p) {
            __half2 sm = __hadd2(__hadd2(g0[p], g1[p]), __hadd2(g2[p], g3[p]));
            float2 f = __half22float2(sm);
            b[2 * p] = f.x;
            b[2 * p + 1] = f.y;
        }
    }
    for (int j = jA + 32; j < eA; j += 8) {  // rare tail: deg > 32
        float4 r = X4[(size_t)scol[j] * 8 + sub];
        const __half2* h = (const __half2*)&r;
#pragma unroll
        for (int p = 0; p < 4; ++p) {
            float2 f = __half22float2(h[p]);
            a[2 * p]     += f.x;
            a[2 * p + 1] += f.y;
        }
    }
    for (int j = jB + 32; j < eB; j += 8) {
        float4 r = X4[(size_t)scol[j] * 8 + sub];
        const __half2* h = (const __half2*)&r;
#pragma unroll
        for (int p = 0; p < 4; ++p) {
            float2 f = __half22float2(h[p]);
            b[2 * p]     += f.x;
            b[2 * p + 1] += f.y;
        }
    }
#pragma unroll
    for (int off = 32; off >= 8; off >>= 1)
#pragma unroll
        for (int k = 0; k < 8; ++k) {
            a[k] += __shfl_down(a[k], off, 64);
            b[k] += __shfl_down(b[k], off, 64);
        }
    if (lane < 8) {
        float invA = (eA > sA) ? 1.0f / (float)(eA - sA) : 1.0f;
        union { __half2 h[4]; float4 f; } u;
        u.h[0] = __floats2half2_rn(a[0] * invA, a[1] * invA);
        u.h[1] = __floats2half2_rn(a[2] * invA, a[3] * invA);
        u.h[2] = __floats2half2_rn(a[4] * invA, a[5] * invA);
        u.h[3] = __floats2half2_rn(a[6] * invA, a[7] * invA);
        *(float4*)(AGGH + (size_t)nA * CH + sub * 8) = u.f;
        if (nB < N) {
            float invB = (eB > sB) ? 1.0f / (float)(eB - sB) : 1.0f;
            union { __half2 h[4]; float4 f; } v;
            v.h[0] = __floats2half2_rn(b[0] * invB, b[1] * invB);
            v.h[1] = __floats2half2_rn(b[2] * invB, b[3] * invB);
            v.h[2] = __floats2half2_rn(b[4] * invB, b[5] * invB);
            v.h[3] = __floats2half2_rn(b[6] * invB, b[7] * invB);
            *(float4*)(AGGH + (size_t)nB * CH + sub * 8) = v.f;
        }
    }
}

// MFMA 16x16x16_f16 layout:
//   A: lane l holds A[l&15][4*(l>>4)+r]
//   B: lane l holds B[4*(l>>4)+r][l&15]   (= W[l&15][4*(l>>4)+r] here)
//   D: lane l holds D[4*(l>>4)+r][l&15]
// Per wave: 32 nodes (2 row-tiles), 64 out channels (4 col-tiles), K=128.

// ---- layer-1: h1 = relu(cat(xh,agg).W1^T + b1), fp16 out ----
__global__ __launch_bounds__(256) void k_gemm(const __half* __restrict__ A,
                                              const __half* __restrict__ AGGH,
                                              const float* __restrict__ W,
                                              const float* __restrict__ bias,
                                              __half* __restrict__ OUT, int N) {
    int w = threadIdx.x >> 6;
    int lane = threadIdx.x & 63;
    int lrow = lane & 15;
    int lk = lane >> 4;
    int nb = blockIdx.x * 128 + w * 32;

    half4_t bfr[4][8];
#pragma unroll
    for (int ct = 0; ct < 4; ++ct) {
        const float* wr = W + (ct * 16 + lrow) * 128 + 4 * lk;
#pragma unroll
        for (int kc = 0; kc < 8; ++kc) {
            float4 v = *(const float4*)(wr + kc * 16);
            half4_t h = {(_Float16)v.x, (_Float16)v.y, (_Float16)v.z, (_Float16)v.w};
            bfr[ct][kc] = h;
        }
    }

#pragma unroll
    for (int t2 = 0; t2 < 2; ++t2) {
        int ar = nb + t2 * 16 + lrow;
        int arx = min(ar, N);      // xh has zeroed dummy row N
        int ara = min(ar, N - 1);  // aggh: clamp to a real row (finite junk, unstored)
        const __half* xrow = A + (size_t)arx * CH + 4 * lk;
        const __half* grow = AGGH + (size_t)ara * CH + 4 * lk;
        half4_t af[8];
#pragma unroll
        for (int kc = 0; kc < 4; ++kc) {
            af[kc]     = *(const half4_t*)(xrow + kc * 16);
            af[kc + 4] = *(const half4_t*)(grow + kc * 16);
        }
        f32x4 acc[4];
#pragma unroll
        for (int ct = 0; ct < 4; ++ct) acc[ct] = (f32x4){0.f, 0.f, 0.f, 0.f};
#pragma unroll
        for (int kc = 0; kc < 8; ++kc)
#pragma unroll
            for (int ct = 0; ct < 4; ++ct)
                acc[ct] = __builtin_amdgcn_mfma_f32_16x16x16f16(af[kc], bfr[ct][kc],
                                                                acc[ct], 0, 0, 0);
#pragma unroll
        for (int ct = 0; ct < 4; ++ct) {
            float bv = bias[ct * 16 + lrow];
#pragma unroll
            for (int r = 0; r < 4; ++r) {
                int gn = nb + t2 * 16 + 4 * lk + r;
                if (gn < N) {
                    float v = fmaxf(acc[ct][r] + bv, 0.f);
                    OUT[(size_t)gn * CH + ct * 16 + lrow] = __float2half(v);
                }
            }
        }
    }
}

// ---- layer-2 + layer-3 dots: t[n]=relu(h2).W3[0:64], s[n]=relu(h2).W3[64:128] ----
__global__ __launch_bounds__(256) void k_gemm2(const __half* __restrict__ A,
                                               const __half* __restrict__ AGGH,
                                               const float* __restrict__ W,
                                               const float* __restrict__ bias,
                                               const float* __restrict__ W3,
                                               float* __restrict__ tarr,
                                               float* __restrict__ sarr, int N) {
    int w = threadIdx.x >> 6;
    int lane = threadIdx.x & 63;
    int lrow = lane & 15;
    int lk = lane >> 4;
    int nb = blockIdx.x * 128 + w * 32;

    half4_t bfr[4][8];
    float bv[4], w3s[4], w3a[4];
#pragma unroll
    for (int ct = 0; ct < 4; ++ct) {
        const float* wr = W + (ct * 16 + lrow) * 128 + 4 * lk;
#pragma unroll
        for (int kc = 0; kc < 8; ++kc) {
            float4 v = *(const float4*)(wr + kc * 16);
            half4_t h = {(_Float16)v.x, (_Float16)v.y, (_Float16)v.z, (_Float16)v.w};
            bfr[ct][kc] = h;
        }
        bv[ct]  = bias[ct * 16 + lrow];
        w3s[ct] = W3[ct * 16 + lrow];
        w3a[ct] = W3[64 + ct * 16 + lrow];
    }

#pragma unroll
    for (int t2 = 0; t2 < 2; ++t2) {
        int ar = nb + t2 * 16 + lrow;
        int arx = min(ar, N);
        int ara = min(ar, N - 1);
        const __half* xrow = A + (size_t)arx * CH + 4 * lk;
        const __half* grow = AGGH + (size_t)ara * CH + 4 * lk;
        half4_t af[8];
#pragma unroll
        for (int kc = 0; kc < 4; ++kc) {
            af[kc]     = *(const half4_t*)(xrow + kc * 16);
            af[kc + 4] = *(const half4_t*)(grow + kc * 16);
        }
        f32x4 acc[4];
#pragma unroll
        for (int ct = 0; ct < 4; ++ct) acc[ct] = (f32x4){0.f, 0.f, 0.f, 0.f};
#pragma unroll
        for (int kc = 0; kc < 8; ++kc)
#pragma unroll
            for (int ct = 0; ct < 4; ++ct)
                acc[ct] = __builtin_amdgcn_mfma_f32_16x16x16f16(af[kc], bfr[ct][kc],
                                                                acc[ct], 0, 0, 0);
#pragma unroll
        for (int r = 0; r < 4; ++r) {
            float tp = 0.f, sp = 0.f;
#pragma unroll
            for (int ct = 0; ct < 4; ++ct) {
                float v = fmaxf(acc[ct][r] + bv[ct], 0.f);
                tp += v * w3s[ct];
                sp += v * w3a[ct];
            }
#pragma unroll
            for (int off = 1; off <= 8; off <<= 1) {
                tp += __shfl_xor(tp, off, 16);
                sp += __shfl_xor(sp, off, 16);
            }
            int gn = nb + t2 * 16 + 4 * lk + r;
            if (lrow == 0 && gn < N) {
                tarr[gn] = tp;
                sarr[gn] = sp;
            }
        }
    }
}

// ---- Final: out[n] = t[n] + mean_j s[col_j] + b3 (4B/edge gather) ----
__global__ __launch_bounds__(256) void k_fin(const float* __restrict__ tarr,
                                             const float* __restrict__ sarr,
                                             const int* __restrict__ loc,
                                             const int* __restrict__ part,
                                             const int* __restrict__ scol,
                                             const float* __restrict__ b3,
                                             float* __restrict__ out, int N) {
    int n = blockIdx.x * 256 + threadIdx.x;
    if (n >= N) return;
    int s, e;
    node_range(loc, part, n, s, e);
    float s0 = 0.f, s1 = 0.f, s2 = 0.f, s3 = 0.f;
    int j = s;
    for (; j + 4 <= e; j += 4) {
        s0 += sarr[scol[j]];
        s1 += sarr[scol[j + 1]];
        s2 += sarr[scol[j + 2]];
        s3 += sarr[scol[j + 3]];
    }
    for (; j < e; ++j) s0 += sarr[scol[j]];
    float inv = (e > s) ? 1.0f / (float)(e - s) : 1.0f;
    out[n] = tarr[n] + ((s0 + s1) + (s2 + s3)) * inv + b3[0];
}

extern "C" void kernel_launch(void* const* d_in, const int* in_sizes, int n_in,
                              void* d_out, int out_size, void* d_ws, size_t ws_size,
                              hipStream_t stream) {
    const float* x   = (const float*)d_in[0];
    const int* eidx  = (const int*)d_in[1];
    const float* W1  = (const float*)d_in[2];
    const float* b1  = (const float*)d_in[3];
    const float* W2  = (const float*)d_in[4];
    const float* b2  = (const float*)d_in[5];
    const float* W3  = (const float*)d_in[6];
    const float* b3  = (const float*)d_in[7];
    float* out = (float*)d_out;

    const int N = in_sizes[0] / CH;
    const int E = in_sizes[1] / 2;
    const int* row = eidx;
    const int* col = eidx + E;

    int e_sz  = ((E + 3) / 4) * 4;
    size_t tbl = (size_t)(N + 1) * CH;  // halves per table (incl. zero row)

    int* scol    = (int*)d_ws;                        // e_sz ints
    __half* xh   = (__half*)(scol + e_sz);            // tbl halves
    __half* h1   = xh + tbl;                          // tbl halves
    __half* aggh = h1 + tbl;                          // N*CH halves
    float* tarr  = (float*)(aggh + (size_t)N * CH);   // N floats
    float* sarr  = tarr + N;                          // N floats
    int* loc     = (int*)(sarr + N);                  // N ints (deg->scan->incl)
    int* part    = loc + ((N + 3) / 4) * 4;           // 512 ints

    int nbA = (N + 255) / 256;       // scanA blocks (<=512 for scanB)
    int per_blk  = (E + NBLK - 1) / NBLK;
    int per_plc  = (E + NPLACE - 1) / NPLACE;
    int abl = (N + 7) / 8;
    int gbl = (N + 127) / 128;

    // CSR build: deg -> scan -> place (post-increment trick on loc)
    hipMemsetAsync(loc, 0, (size_t)N * sizeof(int), stream);
    k_cntcvt<<<NBLK, 256, 0, stream>>>(row, loc, x, xh, h1, E, per_blk,
                                       N * CH, N);
    k_scanA<<<nbA, 256, 0, stream>>>(loc, part, N);
    k_scanB<<<1, 256, 0, stream>>>(part, nbA);
    k_place<<<NPLACE, 256, 0, stream>>>(row, col, loc, part, scol, E, per_plc);

    // layer 1
    k_agg<<<abl, 256, 0, stream>>>((const float4*)xh, loc, part, scol, aggh, N, E - 1);
    k_gemm<<<gbl, 256, 0, stream>>>(xh, aggh, W1, b1, h1, N);
    // layer 2 (+ fused layer-3 dots)
    k_agg<<<abl, 256, 0, stream>>>((const float4*)h1, loc, part, scol, aggh, N, E - 1);
    k_gemm2<<<gbl, 256, 0, stream>>>(h1, aggh, W2, b2, W3, tarr, sarr, N);
    // layer 3 finish
    k_fin<<<(N + 255) / 256, 256, 0, stream>>>(tarr, sarr, loc, part, scol, b3, out, N);
}

// Round 7
// 301.592 us; speedup vs baseline: 2.7246x; 1.4343x over previous
//
#include <hip/hip_runtime.h>
#include <hip/hip_fp16.h>

// GraphSAGE 3-layer (R7) — best-of recombination:
// CSR: bucketed counting sort, single-pass (R3): histcvt saves per-block LDS
//   histogram (hsave) + atomic btot; scatter does local btot-scan + atomic
//   range reservation + ONE pass over row/col; build restores R2's sbuf LDS
//   staging for coalesced scol writes (R6 showed scattered 4B writes cost
//   64B line write-backs: k_place was 150us, WRITE_SIZE 106MB).
// Layers: SPLIT agg/gemm (R3 fusion measured +10us/layer). GEMMs on
//   v_mfma_f32_16x16x16_f16, W converted fp32->fp16 in-register.
// Mega-kernel abandoned: grid barrier ~150-200us at G=1536 (R4/R5).
//
// ws: offs | scol | xh h[(N+1)*64] | h1 h[(N+1)*64] | aggh h[N*64] | tarr | sarr
//     (sort scratch ebuf/btot/cursor/hsave aliases the aggh region)

#define CH 64
#define BKT_SHIFT 9
#define BKT_ROWS 512
#define NBLK 256   // hist/scatter blocks; requires nbk <= 256 (N <= 131072)
#define SCAP 12288 // LDS staging capacity in k_build (avg bucket ~8192)

typedef _Float16 half4_t __attribute__((ext_vector_type(4)));
typedef float f32x4 __attribute__((ext_vector_type(4)));

// ---- Pass A: per-block bucket histogram (saved + global totals), fused
//      with fp32->fp16 table conversion (grid-stride) ----
__global__ __launch_bounds__(256) void k_histcvt(const int* __restrict__ row,
                                                 int* __restrict__ btot,
                                                 int* __restrict__ hsave,
                                                 const float* __restrict__ X,
                                                 __half* __restrict__ XH,
                                                 __half* __restrict__ H1,
                                                 int E, int per_blk,
                                                 int Mf, int N) {
    __shared__ int h[256];
    int t = threadIdx.x;
    h[t] = 0;
    __syncthreads();
    int s = blockIdx.x * per_blk;
    int e = min(s + per_blk, E);
    for (int i = s + t; i < e; i += 256)
        atomicAdd(&h[row[i] >> BKT_SHIFT], 1);
    // fp32 -> fp16 conversion, grid-stride over the whole x table
    for (int idx = (blockIdx.x * 256 + t) * 4; idx < Mf; idx += NBLK * 256 * 4) {
        float4 v = *(const float4*)(X + idx);
        union { __half2 h2[2]; float2 f; } u;
        u.h2[0] = __floats2half2_rn(v.x, v.y);
        u.h2[1] = __floats2half2_rn(v.z, v.w);
        *(float2*)(XH + idx) = u.f;
    }
    if (blockIdx.x == 0 && t < 16) {
        float4 z = {0.f, 0.f, 0.f, 0.f};
        if (t < 8)
            ((float4*)(XH + (size_t)N * CH))[t] = z;
        else
            ((float4*)(H1 + (size_t)N * CH))[t - 8] = z;
    }
    __syncthreads();
    int c = h[t];
    hsave[blockIdx.x * 256 + t] = c;
    if (c) atomicAdd(&btot[t], c);
}

// ---- Pass B: local scan of btot -> bstart; reserve per-bucket ranges via
//      atomic cursor using saved histogram; single placement pass ----
__global__ __launch_bounds__(256) void k_scatter(const int* __restrict__ row,
                                                 const int* __restrict__ col,
                                                 const int* __restrict__ btot,
                                                 int* __restrict__ cursor,
                                                 const int* __restrict__ hsave,
                                                 int* __restrict__ ebuf,
                                                 int E, int per_blk) {
    __shared__ int ts[256];
    __shared__ int base[256];
    __shared__ int h[256];
    int t = threadIdx.x;
    int v = btot[t];
    ts[t] = v;
    __syncthreads();
    for (int off = 1; off < 256; off <<= 1) {
        int u = (t >= off) ? ts[t - off] : 0;
        __syncthreads();
        ts[t] += u;
        __syncthreads();
    }
    int bstart = ts[t] - v;  // exclusive scan
    int cnt = hsave[blockIdx.x * 256 + t];
    base[t] = bstart + (cnt ? atomicAdd(&cursor[t], cnt) : 0);
    h[t] = 0;
    __syncthreads();
    int s = blockIdx.x * per_blk;
    int e = min(s + per_blk, E);
    for (int i = s + t; i < e; i += 256) {
        int r = row[i];
        int b = r >> BKT_SHIFT;
        int p = base[b] + atomicAdd(&h[b], 1);
        ebuf[p] = ((r & (BKT_ROWS - 1)) << 17) | col[i];
    }
}

// ---- Pass C: per-bucket CSR build; local btot scan for bucket range;
//      scol staged in LDS sbuf for coalesced output ----
__global__ __launch_bounds__(256) void k_build(const int* __restrict__ btot,
                                               const int* __restrict__ ebuf,
                                               int* __restrict__ offs,
                                               int* __restrict__ scol,
                                               int N, int E, int nbk) {
    __shared__ int cnt[BKT_ROWS];
    __shared__ int loff[BKT_ROWS];
    __shared__ int ts[256];
    __shared__ int sbuf[SCAP];
    __shared__ int gg[2];
    int b = blockIdx.x, t = threadIdx.x;
    int v = btot[t];
    ts[t] = v;
    __syncthreads();
    for (int off = 1; off < 256; off <<= 1) {
        int u = (t >= off) ? ts[t - off] : 0;
        __syncthreads();
        ts[t] += u;
        __syncthreads();
    }
    if (t == b) { gg[0] = ts[t] - v; gg[1] = ts[t]; }
    __syncthreads();
    int g0 = gg[0], g1 = gg[1];
    cnt[t] = 0;
    cnt[t + 256] = 0;
    __syncthreads();
    for (int i = g0 + t; i < g1; i += 256)
        atomicAdd(&cnt[((unsigned)ebuf[i]) >> 17], 1);
    __syncthreads();
    int c0 = cnt[2 * t], c1 = cnt[2 * t + 1];
    ts[t] = c0 + c1;
    __syncthreads();
    for (int off = 1; off < 256; off <<= 1) {
        int u = (t >= off) ? ts[t - off] : 0;
        __syncthreads();
        ts[t] += u;
        __syncthreads();
    }
    int ex = ts[t] - (c0 + c1);
    loff[2 * t] = ex;
    loff[2 * t + 1] = ex + c0;
    __syncthreads();
    int r0 = b << BKT_SHIFT;
    for (int r = t; r < BKT_ROWS; r += 256)
        if (r0 + r < N) offs[r0 + r] = g0 + loff[r];
    if (b == nbk - 1 && t == 0) offs[N] = E;
    cnt[t] = 0;
    cnt[t + 256] = 0;
    __syncthreads();
    int sz = g1 - g0;
    if (sz <= SCAP) {
        for (int i = g0 + t; i < g1; i += 256) {
            unsigned v2 = (unsigned)ebuf[i];
            int rl = v2 >> 17;
            int p = atomicAdd(&cnt[rl], 1);
            sbuf[loff[rl] + p] = (int)(v2 & 0x1FFFFu);
        }
        __syncthreads();
        for (int i = t; i < sz; i += 256) scol[g0 + i] = sbuf[i];
    } else {
        for (int i = g0 + t; i < g1; i += 256) {
            unsigned v2 = (unsigned)ebuf[i];
            int rl = v2 >> 17;
            int p = atomicAdd(&cnt[rl], 1);
            scol[g0 + loff[rl] + p] = (int)(v2 & 0x1FFFFu);
        }
    }
}

// ---- Mean-aggregate: one wave per 2 nodes, 8 lanes/edge, 8 gathers in
//      flight, clamp-to-zero-row prefetch, pk_f16 pairwise tree sum ----
__global__ __launch_bounds__(256) void k_agg(const float4* __restrict__ X4,
                                             const int* __restrict__ offs,
                                             const int* __restrict__ scol,
                                             __half* __restrict__ AGGH, int N, int Em1) {
    int wv = threadIdx.x >> 6;
    int lane = threadIdx.x & 63;
    int nA = blockIdx.x * 8 + wv * 2;
    if (nA >= N) return;
    int nB = nA + 1;
    int sA = offs[nA], eA = offs[nA + 1];
    int sB = 0, eB = 0;
    if (nB < N) { sB = offs[nB]; eB = offs[nB + 1]; }
    int sub = lane & 7;
    int grp = lane >> 3;
    int jA = sA + grp, jB = sB + grp;
    int a0 = scol[min(jA, Em1)];       a0 = (jA < eA)      ? a0 : N;
    int a1 = scol[min(jA + 8, Em1)];   a1 = (jA + 8 < eA)  ? a1 : N;
    int a2 = scol[min(jA + 16, Em1)];  a2 = (jA + 16 < eA) ? a2 : N;
    int a3 = scol[min(jA + 24, Em1)];  a3 = (jA + 24 < eA) ? a3 : N;
    int b0 = scol[min(jB, Em1)];       b0 = (jB < eB)      ? b0 : N;
    int b1 = scol[min(jB + 8, Em1)];   b1 = (jB + 8 < eB)  ? b1 : N;
    int b2 = scol[min(jB + 16, Em1)];  b2 = (jB + 16 < eB) ? b2 : N;
    int b3 = scol[min(jB + 24, Em1)];  b3 = (jB + 24 < eB) ? b3 : N;
    float4 rA0 = X4[(size_t)a0 * 8 + sub];
    float4 rA1 = X4[(size_t)a1 * 8 + sub];
    float4 rA2 = X4[(size_t)a2 * 8 + sub];
    float4 rA3 = X4[(size_t)a3 * 8 + sub];
    float4 rB0 = X4[(size_t)b0 * 8 + sub];
    float4 rB1 = X4[(size_t)b1 * 8 + sub];
    float4 rB2 = X4[(size_t)b2 * 8 + sub];
    float4 rB3 = X4[(size_t)b3 * 8 + sub];
    float a[8], b[8];
    {
        const __half2* h0 = (const __half2*)&rA0;
        const __half2* h1 = (const __half2*)&rA1;
        const __half2* h2 = (const __half2*)&rA2;
        const __half2* h3 = (const __half2*)&rA3;
#pragma unroll
        for (int p = 0; p < 4; ++p) {
            __half2 sm = __hadd2(__hadd2(h0[p], h1[p]), __hadd2(h2[p], h3[p]));
            float2 f = __half22float2(sm);
            a[2 * p] = f.x;
            a[2 * p + 1] = f.y;
        }
        const __half2* g0 = (const __half2*)&rB0;
        const __half2* g1 = (const __half2*)&rB1;
        const __half2* g2 = (const __half2*)&rB2;
        const __half2* g3 = (const __half2*)&rB3;
#pragma unroll
        for (int p = 0; p < 4; ++p) {
            __half2 sm = __hadd2(__hadd2(g0[p], g1[p]), __hadd2(g2[p], g3[p]));
            float2 f = __half22float2(sm);
            b[2 * p] = f.x;
            b[2 * p + 1] = f.y;
        }
    }
    for (int j = jA + 32; j < eA; j += 8) {  // rare tail: deg > 32
        float4 r = X4[(size_t)scol[j] * 8 + sub];
        const __half2* h = (const __half2*)&r;
#pragma unroll
        for (int p = 0; p < 4; ++p) {
            float2 f = __half22float2(h[p]);
            a[2 * p]     += f.x;
            a[2 * p + 1] += f.y;
        }
    }
    for (int j = jB + 32; j < eB; j += 8) {
        float4 r = X4[(size_t)scol[j] * 8 + sub];
        const __half2* h = (const __half2*)&r;
#pragma unroll
        for (int p = 0; p < 4; ++p) {
            float2 f = __half22float2(h[p]);
            b[2 * p]     += f.x;
            b[2 * p + 1] += f.y;
        }
    }
#pragma unroll
    for (int off = 32; off >= 8; off >>= 1)
#pragma unroll
        for (int k = 0; k < 8; ++k) {
            a[k] += __shfl_down(a[k], off, 64);
            b[k] += __shfl_down(b[k], off, 64);
        }
    if (lane < 8) {
        float invA = (eA > sA) ? 1.0f / (float)(eA - sA) : 1.0f;
        union { __half2 h[4]; float4 f; } u;
        u.h[0] = __floats2half2_rn(a[0] * invA, a[1] * invA);
        u.h[1] = __floats2half2_rn(a[2] * invA, a[3] * invA);
        u.h[2] = __floats2half2_rn(a[4] * invA, a[5] * invA);
        u.h[3] = __floats2half2_rn(a[6] * invA, a[7] * invA);
        *(float4*)(AGGH + (size_t)nA * CH + sub * 8) = u.f;
        if (nB < N) {
            float invB = (eB > sB) ? 1.0f / (float)(eB - sB) : 1.0f;
            union { __half2 h[4]; float4 f; } v;
            v.h[0] = __floats2half2_rn(b[0] * invB, b[1] * invB);
            v.h[1] = __floats2half2_rn(b[2] * invB, b[3] * invB);
            v.h[2] = __floats2half2_rn(b[4] * invB, b[5] * invB);
            v.h[3] = __floats2half2_rn(b[6] * invB, b[7] * invB);
            *(float4*)(AGGH + (size_t)nB * CH + sub * 8) = v.f;
        }
    }
}

// MFMA 16x16x16_f16 layout:
//   A: lane l holds A[l&15][4*(l>>4)+r]
//   B: lane l holds B[4*(l>>4)+r][l&15]   (= W[l&15][4*(l>>4)+r] here)
//   D: lane l holds D[4*(l>>4)+r][l&15]
// Per wave: 32 nodes (2 row-tiles), 64 out channels (4 col-tiles), K=128.

// ---- layer-1: h1 = relu(cat(xh,agg).W1^T + b1), fp16 out ----
__global__ __launch_bounds__(256) void k_gemm(const __half* __restrict__ A,
                                              const __half* __restrict__ AGGH,
                                              const float* __restrict__ W,
                                              const float* __restrict__ bias,
                                              __half* __restrict__ OUT, int N) {
    int w = threadIdx.x >> 6;
    int lane = threadIdx.x & 63;
    int lrow = lane & 15;
    int lk = lane >> 4;
    int nb = blockIdx.x * 128 + w * 32;

    half4_t bfr[4][8];
#pragma unroll
    for (int ct = 0; ct < 4; ++ct) {
        const float* wr = W + (ct * 16 + lrow) * 128 + 4 * lk;
#pragma unroll
        for (int kc = 0; kc < 8; ++kc) {
            float4 v = *(const float4*)(wr + kc * 16);
            half4_t h = {(_Float16)v.x, (_Float16)v.y, (_Float16)v.z, (_Float16)v.w};
            bfr[ct][kc] = h;
        }
    }

#pragma unroll
    for (int t2 = 0; t2 < 2; ++t2) {
        int ar = nb + t2 * 16 + lrow;
        int arx = min(ar, N);      // xh has zeroed dummy row N
        int ara = min(ar, N - 1);  // aggh: clamp to a real row (finite junk, unstored)
        const __half* xrow = A + (size_t)arx * CH + 4 * lk;
        const __half* grow = AGGH + (size_t)ara * CH + 4 * lk;
        half4_t af[8];
#pragma unroll
        for (int kc = 0; kc < 4; ++kc) {
            af[kc]     = *(const half4_t*)(xrow + kc * 16);
            af[kc + 4] = *(const half4_t*)(grow + kc * 16);
        }
        f32x4 acc[4];
#pragma unroll
        for (int ct = 0; ct < 4; ++ct) acc[ct] = (f32x4){0.f, 0.f, 0.f, 0.f};
#pragma unroll
        for (int kc = 0; kc < 8; ++kc)
#pragma unroll
            for (int ct = 0; ct < 4; ++ct)
                acc[ct] = __builtin_amdgcn_mfma_f32_16x16x16f16(af[kc], bfr[ct][kc],
                                                                acc[ct], 0, 0, 0);
#pragma unroll
        for (int ct = 0; ct < 4; ++ct) {
            float bv = bias[ct * 16 + lrow];
#pragma unroll
            for (int r = 0; r < 4; ++r) {
                int gn = nb + t2 * 16 + 4 * lk + r;
                if (gn < N) {
                    float v = fmaxf(acc[ct][r] + bv, 0.f);
                    OUT[(size_t)gn * CH + ct * 16 + lrow] = __float2half(v);
                }
            }
        }
    }
}

// ---- layer-2 + layer-3 dots: t[n]=relu(h2).W3[0:64], s[n]=relu(h2).W3[64:128] ----
__global__ __launch_bounds__(256) void k_gemm2(const __half* __restrict__ A,
                                               const __half* __restrict__ AGGH,
                                               const float* __restrict__ W,
                                               const float* __restrict__ bias,
                                               const float* __restrict__ W3,
                                               float* __restrict__ tarr,
                                               float* __restrict__ sarr, int N) {
    int w = threadIdx.x >> 6;
    int lane = threadIdx.x & 63;
    int lrow = lane & 15;
    int lk = lane >> 4;
    int nb = blockIdx.x * 128 + w * 32;

    half4_t bfr[4][8];
    float bv[4], w3s[4], w3a[4];
#pragma unroll
    for (int ct = 0; ct < 4; ++ct) {
        const float* wr = W + (ct * 16 + lrow) * 128 + 4 * lk;
#pragma unroll
        for (int kc = 0; kc < 8; ++kc) {
            float4 v = *(const float4*)(wr + kc * 16);
            half4_t h = {(_Float16)v.x, (_Float16)v.y, (_Float16)v.z, (_Float16)v.w};
            bfr[ct][kc] = h;
        }
        bv[ct]  = bias[ct * 16 + lrow];
        w3s[ct] = W3[ct * 16 + lrow];
        w3a[ct] = W3[64 + ct * 16 + lrow];
    }

#pragma unroll
    for (int t2 = 0; t2 < 2; ++t2) {
        int ar = nb + t2 * 16 + lrow;
        int arx = min(ar, N);
        int ara = min(ar, N - 1);
        const __half* xrow = A + (size_t)arx * CH + 4 * lk;
        const __half* grow = AGGH + (size_t)ara * CH + 4 * lk;
        half4_t af[8];
#pragma unroll
        for (int kc = 0; kc < 4; ++kc) {
            af[kc]     = *(const half4_t*)(xrow + kc * 16);
            af[kc + 4] = *(const half4_t*)(grow + kc * 16);
        }
        f32x4 acc[4];
#pragma unroll
        for (int ct = 0; ct < 4; ++ct) acc[ct] = (f32x4){0.f, 0.f, 0.f, 0.f};
#pragma unroll
        for (int kc = 0; kc < 8; ++kc)
#pragma unroll
            for (int ct = 0; ct < 4; ++ct)
                acc[ct] = __builtin_amdgcn_mfma_f32_16x16x16f16(af[kc], bfr[ct][kc],
                                                                acc[ct], 0, 0, 0);
#pragma unroll
        for (int r = 0; r < 4; ++r) {
            float tp = 0.f, sp = 0.f;
#pragma unroll
            for (int ct = 0; ct < 4; ++ct) {
                float v = fmaxf(acc[ct][r] + bv[ct], 0.f);
                tp += v * w3s[ct];
                sp += v * w3a[ct];
            }
#pragma unroll
            for (int off = 1; off <= 8; off <<= 1) {
                tp += __shfl_xor(tp, off, 16);
                sp += __shfl_xor(sp, off, 16);
            }
            int gn = nb + t2 * 16 + 4 * lk + r;
            if (lrow == 0 && gn < N) {
                tarr[gn] = tp;
                sarr[gn] = sp;
            }
        }
    }
}

// ---- Final: out[n] = t[n] + mean_j s[col_j] + b3 (4B/edge gather) ----
__global__ __launch_bounds__(256) void k_fin(const float* __restrict__ tarr,
                                             const float* __restrict__ sarr,
                                             const int* __restrict__ offs,
                                             const int* __restrict__ scol,
                                             const float* __restrict__ b3,
                                             float* __restrict__ out, int N) {
    int n = blockIdx.x * 256 + threadIdx.x;
    if (n >= N) return;
    int s = offs[n], e = offs[n + 1];
    float s0 = 0.f, s1 = 0.f, s2 = 0.f, s3 = 0.f;
    int j = s;
    for (; j + 4 <= e; j += 4) {
        s0 += sarr[scol[j]];
        s1 += sarr[scol[j + 1]];
        s2 += sarr[scol[j + 2]];
        s3 += sarr[scol[j + 3]];
    }
    for (; j < e; ++j) s0 += sarr[scol[j]];
    float inv = (e > s) ? 1.0f / (float)(e - s) : 1.0f;
    out[n] = tarr[n] + ((s0 + s1) + (s2 + s3)) * inv + b3[0];
}

extern "C" void kernel_launch(void* const* d_in, const int* in_sizes, int n_in,
                              void* d_out, int out_size, void* d_ws, size_t ws_size,
                              hipStream_t stream) {
    const float* x   = (const float*)d_in[0];
    const int* eidx  = (const int*)d_in[1];
    const float* W1  = (const float*)d_in[2];
    const float* b1  = (const float*)d_in[3];
    const float* W2  = (const float*)d_in[4];
    const float* b2  = (const float*)d_in[5];
    const float* W3  = (const float*)d_in[6];
    const float* b3  = (const float*)d_in[7];
    float* out = (float*)d_out;

    const int N = in_sizes[0] / CH;
    const int E = in_sizes[1] / 2;
    const int* row = eidx;
    const int* col = eidx + E;

    int offs_sz = ((N + 1 + 3) / 4) * 4;
    int e_sz    = ((E + 3) / 4) * 4;
    size_t tbl  = (size_t)(N + 1) * CH;  // halves per table (incl. zero row)

    int* offs    = (int*)d_ws;                        // offs_sz ints
    int* scol    = offs + offs_sz;                    // e_sz ints
    __half* xh   = (__half*)(scol + e_sz);            // tbl halves
    __half* h1   = xh + tbl;                          // tbl halves
    __half* aggh = h1 + tbl;                          // N*CH halves
    float* tarr  = (float*)(aggh + (size_t)N * CH);   // N floats
    float* sarr  = tarr + N;                          // N floats
    // sort scratch aliases aggh region (dead before aggh's first write)
    int* ebuf   = (int*)aggh;                         // E ints
    int nbk     = (N + BKT_ROWS - 1) >> BKT_SHIFT;
    int* btot   = ebuf + e_sz;                        // 256 ints
    int* cursor = btot + 256;                         // 256 ints
    int* hsave  = cursor + 256;                       // 256*256 ints

    int per_blk = (E + NBLK - 1) / NBLK;
    int abl = (N + 7) / 8;
    int gbl = (N + 127) / 128;

    // CSR build (single-pass scatter via saved histograms)
    hipMemsetAsync(btot, 0, 512 * sizeof(int), stream);
    k_histcvt<<<NBLK, 256, 0, stream>>>(row, btot, hsave, x, xh, h1, E, per_blk,
                                        N * CH, N);
    k_scatter<<<NBLK, 256, 0, stream>>>(row, col, btot, cursor, hsave, ebuf, E, per_blk);
    k_build<<<nbk, 256, 0, stream>>>(btot, ebuf, offs, scol, N, E, nbk);

    // layer 1
    k_agg<<<abl, 256, 0, stream>>>((const float4*)xh, offs, scol, aggh, N, E - 1);
    k_gemm<<<gbl, 256, 0, stream>>>(xh, aggh, W1, b1, h1, N);
    // layer 2 (+ fused layer-3 dots)
    k_agg<<<abl, 256, 0, stream>>>((const float4*)h1, offs, scol, aggh, N, E - 1);
    k_gemm2<<<gbl, 256, 0, stream>>>(h1, aggh, W2, b2, W3, tarr, sarr, N);
    // layer 3 finish
    k_fin<<<(N + 255) / 256, 256, 0, stream>>>(tarr, sarr, offs, scol, b3, out, N);
}

// Round 8
// 286.429 us; speedup vs baseline: 2.8689x; 1.0529x over previous
//
#include <hip/hip_runtime.h>
#include <hip/hip_fp16.h>

// GraphSAGE 3-layer (R8). Fused agg+GEMM per layer (R3 structure — measured
// better at wall level than split despite longer kernel), with two fixes:
//  (a) NO block barrier between agg and MFMA: alds rows are WAVE-PRIVATE
//      (wave wv aggregates rows wv*16..+15 and its MFMA reads exactly those).
//      Only wlds needs a sync, done once up front. Stragglers no longer gate
//      the block; MFMA overlaps other waves' gathers.
//  (b) pair loop unroll 2: 16 gather loads in flight per wave (was 8).
// CSR: R3/R7 single-pass bucket sort (histcvt+hsave -> scatter -> build with
// LDS sbuf staging; R6 proved scattered 4B stores cost 64B line write-backs).
// Mega-kernel abandoned (R4/R5: grid barrier ~100+us at G=1536).
//
// ws: offs | scol | xh h[(N+1)*64] | h1 h[(N+1)*64] | scr | tarr f[N] | sarr f[N]
//     scr = ebuf[E] | btot[256] | cursor[256] | hsave[256*256]

#define CH 64
#define BKT_SHIFT 9
#define BKT_ROWS 512
#define NBLK 256   // hist/scatter blocks; requires nbk <= 256 (N <= 131072)
#define SCAP 12288 // LDS staging capacity in k_build (avg bucket ~8192)

typedef _Float16 half4_t __attribute__((ext_vector_type(4)));
typedef float f32x4 __attribute__((ext_vector_type(4)));

#define ALDS_STRIDE 72   // halves; 144B rows: 16B-aligned, <=2-way banks
#define WLDS_STRIDE 132  // halves; 264B rows: 8B-aligned, <=2-way banks

// ---- Pass A: per-block bucket histogram (saved + global totals), fused
//      with fp32->fp16 table conversion (grid-stride) ----
__global__ __launch_bounds__(256) void k_histcvt(const int* __restrict__ row,
                                                 int* __restrict__ btot,
                                                 int* __restrict__ hsave,
                                                 const float* __restrict__ X,
                                                 __half* __restrict__ XH,
                                                 __half* __restrict__ H1,
                                                 int E, int per_blk,
                                                 int Mf, int N) {
    __shared__ int h[256];
    int t = threadIdx.x;
    h[t] = 0;
    __syncthreads();
    int s = blockIdx.x * per_blk;
    int e = min(s + per_blk, E);
    for (int i = s + t; i < e; i += 256)
        atomicAdd(&h[row[i] >> BKT_SHIFT], 1);
    for (int idx = (blockIdx.x * 256 + t) * 4; idx < Mf; idx += NBLK * 256 * 4) {
        float4 v = *(const float4*)(X + idx);
        union { __half2 h2[2]; float2 f; } u;
        u.h2[0] = __floats2half2_rn(v.x, v.y);
        u.h2[1] = __floats2half2_rn(v.z, v.w);
        *(float2*)(XH + idx) = u.f;
    }
    if (blockIdx.x == 0 && t < 16) {
        float4 z = {0.f, 0.f, 0.f, 0.f};
        if (t < 8)
            ((float4*)(XH + (size_t)N * CH))[t] = z;
        else
            ((float4*)(H1 + (size_t)N * CH))[t - 8] = z;
    }
    __syncthreads();
    int c = h[t];
    hsave[blockIdx.x * 256 + t] = c;
    if (c) atomicAdd(&btot[t], c);
}

// ---- Pass B: local scan of btot -> bstart; reserve per-bucket ranges via
//      atomic cursor using saved histogram; single placement pass ----
__global__ __launch_bounds__(256) void k_scatter(const int* __restrict__ row,
                                                 const int* __restrict__ col,
                                                 const int* __restrict__ btot,
                                                 int* __restrict__ cursor,
                                                 const int* __restrict__ hsave,
                                                 int* __restrict__ ebuf,
                                                 int E, int per_blk) {
    __shared__ int ts[256];
    __shared__ int base[256];
    __shared__ int h[256];
    int t = threadIdx.x;
    int v = btot[t];
    ts[t] = v;
    __syncthreads();
    for (int off = 1; off < 256; off <<= 1) {
        int u = (t >= off) ? ts[t - off] : 0;
        __syncthreads();
        ts[t] += u;
        __syncthreads();
    }
    int bstart = ts[t] - v;  // exclusive scan
    int cnt = hsave[blockIdx.x * 256 + t];
    base[t] = bstart + (cnt ? atomicAdd(&cursor[t], cnt) : 0);
    h[t] = 0;
    __syncthreads();
    int s = blockIdx.x * per_blk;
    int e = min(s + per_blk, E);
    for (int i = s + t; i < e; i += 256) {
        int r = row[i];
        int b = r >> BKT_SHIFT;
        int p = base[b] + atomicAdd(&h[b], 1);
        ebuf[p] = ((r & (BKT_ROWS - 1)) << 17) | col[i];
    }
}

// ---- Pass C: per-bucket CSR build; local btot scan for bucket range;
//      scol staged in LDS sbuf for coalesced output ----
__global__ __launch_bounds__(256) void k_build(const int* __restrict__ btot,
                                               const int* __restrict__ ebuf,
                                               int* __restrict__ offs,
                                               int* __restrict__ scol,
                                               int N, int E, int nbk) {
    __shared__ int cnt[BKT_ROWS];
    __shared__ int loff[BKT_ROWS];
    __shared__ int ts[256];
    __shared__ int sbuf[SCAP];
    __shared__ int gg[2];
    int b = blockIdx.x, t = threadIdx.x;
    int v = btot[t];
    ts[t] = v;
    __syncthreads();
    for (int off = 1; off < 256; off <<= 1) {
        int u = (t >= off) ? ts[t - off] : 0;
        __syncthreads();
        ts[t] += u;
        __syncthreads();
    }
    if (t == b) { gg[0] = ts[t] - v; gg[1] = ts[t]; }
    __syncthreads();
    int g0 = gg[0], g1 = gg[1];
    cnt[t] = 0;
    cnt[t + 256] = 0;
    __syncthreads();
    for (int i = g0 + t; i < g1; i += 256)
        atomicAdd(&cnt[((unsigned)ebuf[i]) >> 17], 1);
    __syncthreads();
    int c0 = cnt[2 * t], c1 = cnt[2 * t + 1];
    ts[t] = c0 + c1;
    __syncthreads();
    for (int off = 1; off < 256; off <<= 1) {
        int u = (t >= off) ? ts[t - off] : 0;
        __syncthreads();
        ts[t] += u;
        __syncthreads();
    }
    int ex = ts[t] - (c0 + c1);
    loff[2 * t] = ex;
    loff[2 * t + 1] = ex + c0;
    __syncthreads();
    int r0 = b << BKT_SHIFT;
    for (int r = t; r < BKT_ROWS; r += 256)
        if (r0 + r < N) offs[r0 + r] = g0 + loff[r];
    if (b == nbk - 1 && t == 0) offs[N] = E;
    cnt[t] = 0;
    cnt[t + 256] = 0;
    __syncthreads();
    int sz = g1 - g0;
    if (sz <= SCAP) {
        for (int i = g0 + t; i < g1; i += 256) {
            unsigned v2 = (unsigned)ebuf[i];
            int rl = v2 >> 17;
            int p = atomicAdd(&cnt[rl], 1);
            sbuf[loff[rl] + p] = (int)(v2 & 0x1FFFFu);
        }
        __syncthreads();
        for (int i = t; i < sz; i += 256) scol[g0 + i] = sbuf[i];
    } else {
        for (int i = g0 + t; i < g1; i += 256) {
            unsigned v2 = (unsigned)ebuf[i];
            int rl = v2 >> 17;
            int p = atomicAdd(&cnt[rl], 1);
            scol[g0 + loff[rl] + p] = (int)(v2 & 0x1FFFFu);
        }
    }
}

// ---- mean-aggregate a node pair into LDS rows rA, rA+1 (fp16) ----
__device__ __forceinline__ void agg_pair(const float4* __restrict__ X4,
                                         const int* __restrict__ offs,
                                         const int* __restrict__ scol,
                                         __half* __restrict__ alds,
                                         int nA, int rA, int lane,
                                         int N, int Em1) {
    int nB = nA + 1;
    int sA = 0, eA = 0, sB = 0, eB = 0;
    if (nA < N) { sA = offs[nA]; eA = offs[nA + 1]; }
    if (nB < N) { sB = offs[nB]; eB = offs[nB + 1]; }
    int sub = lane & 7;
    int grp = lane >> 3;
    int jA = sA + grp, jB = sB + grp;
    int a0 = scol[min(jA, Em1)];       a0 = (jA < eA)      ? a0 : N;
    int a1 = scol[min(jA + 8, Em1)];   a1 = (jA + 8 < eA)  ? a1 : N;
    int a2 = scol[min(jA + 16, Em1)];  a2 = (jA + 16 < eA) ? a2 : N;
    int a3 = scol[min(jA + 24, Em1)];  a3 = (jA + 24 < eA) ? a3 : N;
    int b0 = scol[min(jB, Em1)];       b0 = (jB < eB)      ? b0 : N;
    int b1 = scol[min(jB + 8, Em1)];   b1 = (jB + 8 < eB)  ? b1 : N;
    int b2 = scol[min(jB + 16, Em1)];  b2 = (jB + 16 < eB) ? b2 : N;
    int b3 = scol[min(jB + 24, Em1)];  b3 = (jB + 24 < eB) ? b3 : N;
    float4 rA0 = X4[(size_t)a0 * 8 + sub];
    float4 rA1 = X4[(size_t)a1 * 8 + sub];
    float4 rA2 = X4[(size_t)a2 * 8 + sub];
    float4 rA3 = X4[(size_t)a3 * 8 + sub];
    float4 rB0 = X4[(size_t)b0 * 8 + sub];
    float4 rB1 = X4[(size_t)b1 * 8 + sub];
    float4 rB2 = X4[(size_t)b2 * 8 + sub];
    float4 rB3 = X4[(size_t)b3 * 8 + sub];
    float a[8], b[8];
    {
        const __half2* h0 = (const __half2*)&rA0;
        const __half2* h1 = (const __half2*)&rA1;
        const __half2* h2 = (const __half2*)&rA2;
        const __half2* h3 = (const __half2*)&rA3;
#pragma unroll
        for (int p = 0; p < 4; ++p) {
            __half2 sm = __hadd2(__hadd2(h0[p], h1[p]), __hadd2(h2[p], h3[p]));
            float2 f = __half22float2(sm);
            a[2 * p] = f.x;
            a[2 * p + 1] = f.y;
        }
        const __half2* g0 = (const __half2*)&rB0;
        const __half2* g1 = (const __half2*)&rB1;
        const __half2* g2 = (const __half2*)&rB2;
        const __half2* g3 = (const __half2*)&rB3;
#pragma unroll
        for (int p = 0; p < 4; ++p) {
            __half2 sm = __hadd2(__hadd2(g0[p], g1[p]), __hadd2(g2[p], g3[p]));
            float2 f = __half22float2(sm);
            b[2 * p] = f.x;
            b[2 * p + 1] = f.y;
        }
    }
    for (int j = jA + 32; j < eA; j += 8) {  // rare tail: deg > 32
        float4 r = X4[(size_t)scol[j] * 8 + sub];
        const __half2* h = (const __half2*)&r;
#pragma unroll
        for (int p = 0; p < 4; ++p) {
            float2 f = __half22float2(h[p]);
            a[2 * p]     += f.x;
            a[2 * p + 1] += f.y;
        }
    }
    for (int j = jB + 32; j < eB; j += 8) {
        float4 r = X4[(size_t)scol[j] * 8 + sub];
        const __half2* h = (const __half2*)&r;
#pragma unroll
        for (int p = 0; p < 4; ++p) {
            float2 f = __half22float2(h[p]);
            b[2 * p]     += f.x;
            b[2 * p + 1] += f.y;
        }
    }
#pragma unroll
    for (int off = 32; off >= 8; off >>= 1)
#pragma unroll
        for (int k = 0; k < 8; ++k) {
            a[k] += __shfl_down(a[k], off, 64);
            b[k] += __shfl_down(b[k], off, 64);
        }
    if (lane < 8) {
        float invA = (eA > sA) ? 1.0f / (float)(eA - sA) : 1.0f;
        float invB = (eB > sB) ? 1.0f / (float)(eB - sB) : 1.0f;
        union { __half2 h[4]; float4 f; } u;
        u.h[0] = __floats2half2_rn(a[0] * invA, a[1] * invA);
        u.h[1] = __floats2half2_rn(a[2] * invA, a[3] * invA);
        u.h[2] = __floats2half2_rn(a[4] * invA, a[5] * invA);
        u.h[3] = __floats2half2_rn(a[6] * invA, a[7] * invA);
        *(float4*)(alds + rA * ALDS_STRIDE + sub * 8) = u.f;
        union { __half2 h[4]; float4 f; } w;
        w.h[0] = __floats2half2_rn(b[0] * invB, b[1] * invB);
        w.h[1] = __floats2half2_rn(b[2] * invB, b[3] * invB);
        w.h[2] = __floats2half2_rn(b[4] * invB, b[5] * invB);
        w.h[3] = __floats2half2_rn(b[6] * invB, b[7] * invB);
        *(float4*)(alds + (rA + 1) * ALDS_STRIDE + sub * 8) = w.f;
    }
}

// ---- convert W (64x128 fp32) into LDS fp16, stride-padded ----
__device__ __forceinline__ void w_to_lds(const float* __restrict__ W,
                                         __half* __restrict__ wlds, int t) {
    for (int i = t; i < 64 * 32; i += 256) {
        int o = i >> 5;
        int kq = (i & 31) * 4;
        float4 v = *(const float4*)(W + o * 128 + kq);
        half4_t h = {(_Float16)v.x, (_Float16)v.y, (_Float16)v.z, (_Float16)v.w};
        *(half4_t*)(wlds + o * WLDS_STRIDE + kq) = h;
    }
}

// wave-local fence: alds writes (lanes 0-7) -> alds reads (all lanes), same wave
__device__ __forceinline__ void wave_lds_fence() {
    __builtin_amdgcn_wave_barrier();
    asm volatile("s_waitcnt lgkmcnt(0)" ::: "memory");
    __builtin_amdgcn_wave_barrier();
}

// MFMA 16x16x16_f16 layout:
//   A: lane l holds A[l&15][4*(l>>4)+r]
//   B: lane l holds B[4*(l>>4)+r][l&15]   (= W[l&15][4*(l>>4)+r] here)
//   D: lane l holds D[4*(l>>4)+r][l&15]

// ---- fused layer-1: agg->LDS (wave-private rows), h1 = relu(cat.W1^T+b1) ----
__global__ __launch_bounds__(256, 4) void k_aggemm1(const float4* __restrict__ X4,
                                                    const __half* __restrict__ XH,
                                                    const int* __restrict__ offs,
                                                    const int* __restrict__ scol,
                                                    const float* __restrict__ W,
                                                    const float* __restrict__ bias,
                                                    __half* __restrict__ OUT,
                                                    int N, int Em1) {
    __shared__ __half alds[64 * ALDS_STRIDE];
    __shared__ __half wlds[64 * WLDS_STRIDE];
    int t = threadIdx.x;
    int wv = t >> 6;
    int lane = t & 63;
    int nb = blockIdx.x * 64;
    w_to_lds(W, wlds, t);
    __syncthreads();  // wlds ready; alds rows are wave-private from here on
#pragma unroll 2
    for (int i = 0; i < 8; ++i) {
        int rA = wv * 16 + 2 * i;
        agg_pair(X4, offs, scol, alds, nb + rA, rA, lane, N, Em1);
    }
    wave_lds_fence();  // this wave's alds rows complete; no block barrier
    int lrow = lane & 15;
    int lk = lane >> 4;
    int nt = nb + wv * 16;
    const __half* xrow = XH + (size_t)min(nt + lrow, N) * CH + 4 * lk;
    half4_t af[8];
#pragma unroll
    for (int kc = 0; kc < 4; ++kc) {
        af[kc]     = *(const half4_t*)(xrow + kc * 16);
        af[kc + 4] = *(const half4_t*)(alds + (wv * 16 + lrow) * ALDS_STRIDE + kc * 16 + 4 * lk);
    }
    f32x4 acc[4];
#pragma unroll
    for (int ct = 0; ct < 4; ++ct) acc[ct] = (f32x4){0.f, 0.f, 0.f, 0.f};
#pragma unroll
    for (int kc = 0; kc < 8; ++kc)
#pragma unroll
        for (int ct = 0; ct < 4; ++ct) {
            half4_t bf = *(const half4_t*)(wlds + (ct * 16 + lrow) * WLDS_STRIDE + kc * 16 + 4 * lk);
            acc[ct] = __builtin_amdgcn_mfma_f32_16x16x16f16(af[kc], bf, acc[ct], 0, 0, 0);
        }
#pragma unroll
    for (int ct = 0; ct < 4; ++ct) {
        float bv = bias[ct * 16 + lrow];
#pragma unroll
        for (int r = 0; r < 4; ++r) {
            int gn = nt + 4 * lk + r;
            if (gn < N) {
                float v = fmaxf(acc[ct][r] + bv, 0.f);
                OUT[(size_t)gn * CH + ct * 16 + lrow] = __float2half(v);
            }
        }
    }
}

// ---- fused layer-2 (+ layer-3 dots): agg->LDS, GEMM, W3 dots -> tarr/sarr ----
__global__ __launch_bounds__(256, 4) void k_aggemm2(const float4* __restrict__ X4,
                                                    const __half* __restrict__ XH,
                                                    const int* __restrict__ offs,
                                                    const int* __restrict__ scol,
                                                    const float* __restrict__ W,
                                                    const float* __restrict__ bias,
                                                    const float* __restrict__ W3,
                                                    float* __restrict__ tarr,
                                                    float* __restrict__ sarr,
                                                    int N, int Em1) {
    __shared__ __half alds[64 * ALDS_STRIDE];
    __shared__ __half wlds[64 * WLDS_STRIDE];
    int t = threadIdx.x;
    int wv = t >> 6;
    int lane = t & 63;
    int nb = blockIdx.x * 64;
    w_to_lds(W, wlds, t);
    __syncthreads();
#pragma unroll 2
    for (int i = 0; i < 8; ++i) {
        int rA = wv * 16 + 2 * i;
        agg_pair(X4, offs, scol, alds, nb + rA, rA, lane, N, Em1);
    }
    wave_lds_fence();
    int lrow = lane & 15;
    int lk = lane >> 4;
    int nt = nb + wv * 16;
    const __half* xrow = XH + (size_t)min(nt + lrow, N) * CH + 4 * lk;
    half4_t af[8];
#pragma unroll
    for (int kc = 0; kc < 4; ++kc) {
        af[kc]     = *(const half4_t*)(xrow + kc * 16);
        af[kc + 4] = *(const half4_t*)(alds + (wv * 16 + lrow) * ALDS_STRIDE + kc * 16 + 4 * lk);
    }
    f32x4 acc[4];
#pragma unroll
    for (int ct = 0; ct < 4; ++ct) acc[ct] = (f32x4){0.f, 0.f, 0.f, 0.f};
#pragma unroll
    for (int kc = 0; kc < 8; ++kc)
#pragma unroll
        for (int ct = 0; ct < 4; ++ct) {
            half4_t bf = *(const half4_t*)(wlds + (ct * 16 + lrow) * WLDS_STRIDE + kc * 16 + 4 * lk);
            acc[ct] = __builtin_amdgcn_mfma_f32_16x16x16f16(af[kc], bf, acc[ct], 0, 0, 0);
        }
    float bv[4], w3s[4], w3a[4];
#pragma unroll
    for (int ct = 0; ct < 4; ++ct) {
        bv[ct]  = bias[ct * 16 + lrow];
        w3s[ct] = W3[ct * 16 + lrow];
        w3a[ct] = W3[64 + ct * 16 + lrow];
    }
#pragma unroll
    for (int r = 0; r < 4; ++r) {
        float tp = 0.f, sp = 0.f;
#pragma unroll
        for (int ct = 0; ct < 4; ++ct) {
            float v = fmaxf(acc[ct][r] + bv[ct], 0.f);
            tp += v * w3s[ct];
            sp += v * w3a[ct];
        }
#pragma unroll
        for (int off = 1; off <= 8; off <<= 1) {
            tp += __shfl_xor(tp, off, 16);
            sp += __shfl_xor(sp, off, 16);
        }
        int gn = nt + 4 * lk + r;
        if (lrow == 0 && gn < N) {
            tarr[gn] = tp;
            sarr[gn] = sp;
        }
    }
}

// ---- Final: out[n] = t[n] + mean_j s[col_j] + b3 (4B/edge gather) ----
__global__ __launch_bounds__(256) void k_fin(const float* __restrict__ tarr,
                                             const float* __restrict__ sarr,
                                             const int* __restrict__ offs,
                                             const int* __restrict__ scol,
                                             const float* __restrict__ b3,
                                             float* __restrict__ out, int N) {
    int n = blockIdx.x * 256 + threadIdx.x;
    if (n >= N) return;
    int s = offs[n], e = offs[n + 1];
    float s0 = 0.f, s1 = 0.f, s2 = 0.f, s3 = 0.f;
    int j = s;
    for (; j + 4 <= e; j += 4) {
        s0 += sarr[scol[j]];
        s1 += sarr[scol[j + 1]];
        s2 += sarr[scol[j + 2]];
        s3 += sarr[scol[j + 3]];
    }
    for (; j < e; ++j) s0 += sarr[scol[j]];
    float inv = (e > s) ? 1.0f / (float)(e - s) : 1.0f;
    out[n] = tarr[n] + ((s0 + s1) + (s2 + s3)) * inv + b3[0];
}

extern "C" void kernel_launch(void* const* d_in, const int* in_sizes, int n_in,
                              void* d_out, int out_size, void* d_ws, size_t ws_size,
                              hipStream_t stream) {
    const float* x   = (const float*)d_in[0];
    const int* eidx  = (const int*)d_in[1];
    const float* W1  = (const float*)d_in[2];
    const float* b1  = (const float*)d_in[3];
    const float* W2  = (const float*)d_in[4];
    const float* b2  = (const float*)d_in[5];
    const float* W3  = (const float*)d_in[6];
    const float* b3  = (const float*)d_in[7];
    float* out = (float*)d_out;

    const int N = in_sizes[0] / CH;
    const int E = in_sizes[1] / 2;
    const int* row = eidx;
    const int* col = eidx + E;

    int offs_sz = ((N + 1 + 3) / 4) * 4;
    int e_sz    = ((E + 3) / 4) * 4;
    size_t tbl  = (size_t)(N + 1) * CH;  // halves per table (incl. zero row)

    int* offs    = (int*)d_ws;                        // offs_sz ints
    int* scol    = offs + offs_sz;                    // e_sz ints
    __half* xh   = (__half*)(scol + e_sz);            // tbl halves
    __half* h1   = xh + tbl;                          // tbl halves
    __half* scr  = h1 + tbl;                          // scratch region (N*CH halves)
    float* tarr  = (float*)(scr + (size_t)N * CH);    // N floats
    float* sarr  = tarr + N;                          // N floats
    // sort scratch inside scr (dead before tarr/sarr written)
    int* ebuf   = (int*)scr;                          // E ints
    int nbk     = (N + BKT_ROWS - 1) >> BKT_SHIFT;
    int* btot   = ebuf + e_sz;                        // 256 ints
    int* cursor = btot + 256;                         // 256 ints
    int* hsave  = cursor + 256;                       // 256*256 ints

    int per_blk = (E + NBLK - 1) / NBLK;
    int gbl = (N + 63) / 64;

    // CSR build (single-pass scatter via saved histograms)
    hipMemsetAsync(btot, 0, 512 * sizeof(int), stream);
    k_histcvt<<<NBLK, 256, 0, stream>>>(row, btot, hsave, x, xh, h1, E, per_blk,
                                        N * CH, N);
    k_scatter<<<NBLK, 256, 0, stream>>>(row, col, btot, cursor, hsave, ebuf, E, per_blk);
    k_build<<<nbk, 256, 0, stream>>>(btot, ebuf, offs, scol, N, E, nbk);

    // layer 1 (agg + GEMM fused, barrier-free)
    k_aggemm1<<<gbl, 256, 0, stream>>>((const float4*)xh, xh, offs, scol,
                                       W1, b1, h1, N, E - 1);
    // layer 2 + layer-3 dots (agg + GEMM fused, barrier-free)
    k_aggemm2<<<gbl, 256, 0, stream>>>((const float4*)h1, h1, offs, scol,
                                       W2, b2, W3, tarr, sarr, N, E - 1);
    // layer 3 finish
    k_fin<<<(N + 255) / 256, 256, 0, stream>>>(tarr, sarr, offs, scol, b3, out, N);
}